// Round 1
// 4321.672 us; speedup vs baseline: 1.0206x; 1.0206x over previous
//
#include <hip/hip_runtime.h>
#include <math.h>

#define DEV __device__ __forceinline__

constexpr int BATCH = 2;
constexpr int L0 = 4096;
constexpr int LS1 = 2048;
constexpr int LS2 = 1024;
constexpr int SEQ = 1024;
constexpr int DM = 768;
constexpr int NH = 24;
constexpr int HD = 64;
constexpr int DI = 1536;
constexpr int DSTATE = 128;
constexpr int CDIM = 1792;   // DI + 2*DSTATE
constexpr int PDIM = 3352;   // 2*DI + 2*DSTATE + NH
constexpr int PPAD = 3456;   // PDIM padded to 27*128
constexpr int CHUNKC = 256;
constexpr int NCH = 4;
constexpr int NLAYER = 24;
constexpr float EPSF = 1e-5f;

typedef short bf16x8 __attribute__((ext_vector_type(8)));
typedef float f32x4 __attribute__((ext_vector_type(4)));

DEV float sigmoidf_(float x){ return 1.f/(1.f+expf(-x)); }
DEV float siluf_(float x){ return x*sigmoidf_(x); }
DEV float geluf_(float x){ return 0.5f*x*(1.f+erff(x*0.70710678118654752440f)); }
DEV float softplusf_(float x){ return fmaxf(x,0.f) + log1pf(expf(-fabsf(x))); }

DEV unsigned short f2bf(float x){
  union { float f; unsigned int u; } v; v.f = x;
  unsigned int u = v.u;
  unsigned int r = (u + 0x7fffu + ((u>>16)&1u)) >> 16;
  return (unsigned short)r;
}
DEV float bf2f(unsigned short u){
  union { unsigned int u; float f; } v; v.u = ((unsigned int)u)<<16; return v.f;
}

DEV void load_lds16(const void* g, void* l){
  __builtin_amdgcn_global_load_lds(
      (const __attribute__((address_space(1))) unsigned int*)g,
      (__attribute__((address_space(3))) unsigned int*)l,
      16, 0, 0);
}

DEV float block_sum_256(float v, float* red4){
  #pragma unroll
  for (int o=32;o>0;o>>=1) v += __shfl_down(v,o,64);
  int tid = threadIdx.x;
  __syncthreads();
  if ((tid&63)==0) red4[tid>>6]=v;
  __syncthreads();
  return red4[0]+red4[1]+red4[2]+red4[3];
}

// ---------------- stem ----------------
__global__ __launch_bounds__(256) void conv_stem1(const float* __restrict__ x,
    const float* __restrict__ w, const float* __restrict__ bias,
    const float* __restrict__ g, const float* __restrict__ bb,
    const float* __restrict__ mn, const float* __restrict__ vr,
    float* __restrict__ out){
  int idx = blockIdx.x*256+threadIdx.x;
  if (idx >= BATCH*192*LS1) return;
  int lo = idx & (LS1-1);
  int co = (idx >> 11) % 192;
  int b  = idx / (192*LS1);
  float s = bias[co];
  const float* wr = w + co*60;
  #pragma unroll
  for (int ci=0; ci<12; ci++){
    const float* xr = x + ((size_t)(b*12+ci))*L0;
    #pragma unroll
    for (int k=0;k<5;k++){
      int li = lo*2 + k - 2;
      if (li>=0 && li<L0) s += wr[ci*5+k]*xr[li];
    }
  }
  s = geluf_(s);
  s = (s-mn[co])*(g[co]*rsqrtf(vr[co]+EPSF)) + bb[co];
  out[idx] = s;
}

__global__ __launch_bounds__(256) void conv_stem2(const float* __restrict__ x,
    const float* __restrict__ w, const float* __restrict__ bias,
    const float* __restrict__ g, const float* __restrict__ bb,
    const float* __restrict__ mn, const float* __restrict__ vr,
    float* __restrict__ out){
  int idx = blockIdx.x*256+threadIdx.x;
  if (idx >= BATCH*384*LS2) return;
  int lo = idx & (LS2-1);
  int co = (idx >> 10) % 384;
  int b  = idx / (384*LS2);
  float s = bias[co];
  const float* wr = w + co*(192*3);
  const float* xb = x + (size_t)b*192*LS1;
  for (int ci=0; ci<192; ci++){
    const float* base = xb + ci*LS1;
    int l2 = lo*2;
    s += wr[ci*3+1]*base[l2];
    s += wr[ci*3+2]*base[l2+1];
    if (lo>0) s += wr[ci*3]*base[l2-1];
  }
  s = geluf_(s);
  s = (s-mn[co])*(g[co]*rsqrtf(vr[co]+EPSF)) + bb[co];
  out[idx] = s;
}

__global__ __launch_bounds__(256) void conv_stem3(const float* __restrict__ x,
    const float* __restrict__ w, const float* __restrict__ bias,
    const float* __restrict__ g, const float* __restrict__ bb,
    const float* __restrict__ mn, const float* __restrict__ vr,
    float* __restrict__ h){
  int co = blockIdx.x % 768;
  int b  = blockIdx.x / 768;
  __shared__ float wsh[384*3];
  for (int t=threadIdx.x; t<384*3; t+=256) wsh[t] = w[(size_t)co*1152 + t];
  __syncthreads();
  const float* xb = x + (size_t)b*384*LS2;
  float scale = g[co]*rsqrtf(vr[co]+EPSF);
  float bnb = bb[co], bnm = mn[co], bs0 = bias[co];
  #pragma unroll
  for (int s=0;s<4;s++){
    int lo = s*256 + threadIdx.x;
    int offm = (lo>0)? -1 : 0;        float mm = (lo>0)? 1.f : 0.f;
    int offp = (lo<LS2-1)? 1 : 0;     float mp = (lo<LS2-1)? 1.f : 0.f;
    float acc = bs0;
    for (int ci=0; ci<384; ci++){
      const float* xr = xb + ci*LS2 + lo;
      float w0=wsh[ci*3+0], w1=wsh[ci*3+1], w2=wsh[ci*3+2];
      acc += w1*xr[0];
      acc += mm*w0*xr[offm];
      acc += mp*w2*xr[offp];
    }
    acc = geluf_(acc);
    acc = (acc-bnm)*scale + bnb;
    h[((size_t)(b*SEQ+lo))*DM + co] = acc;
  }
}

// ---------------- rmsnorm (D=768) ----------------
template<int BF>
__global__ __launch_bounds__(256) void rmsnorm768(const float* __restrict__ in,
    const float* __restrict__ w, float* __restrict__ outf, unsigned short* __restrict__ outb){
  int row = blockIdx.x;
  const float* p = in + (size_t)row*DM;
  float v0[3]; float ss=0.f;
  #pragma unroll
  for (int t=0;t<3;t++){ float q = p[threadIdx.x + t*256]; v0[t]=q; ss+=q*q; }
  __shared__ float red[4];
  float tot = block_sum_256(ss, red);
  float sc = rsqrtf(tot*(1.f/DM) + EPSF);
  #pragma unroll
  for (int t=0;t<3;t++){
    int d = threadIdx.x + t*256;
    float o = v0[t]*sc*w[d];
    if (BF) outb[(size_t)row*DM + d] = f2bf(o);
    else    outf[(size_t)row*DM + d] = o;
  }
}

// ------- transpose + fp32->bf16, batched over layers via blockIdx.z ------------
// rsc: optional per-input-row scale (used to fold gnw into out_proj weight)
__global__ __launch_bounds__(256) void transpose_cvt_l(const float* __restrict__ in0,
    unsigned short* __restrict__ out0, int R, int Cin, int Cpad,
    size_t in_lstride, size_t out_lstride,
    const float* __restrict__ rsc, size_t rsc_stride){
  const float* in = in0 + (size_t)blockIdx.z*in_lstride;
  unsigned short* out = out0 + (size_t)blockIdx.z*out_lstride;
  const float* rs = rsc ? (rsc + (size_t)blockIdx.z*rsc_stride) : nullptr;
  __shared__ float t[32][33];
  int c0 = blockIdx.x*32, r0 = blockIdx.y*32;
  int tx = threadIdx.x & 31, ty = threadIdx.x >> 5;
  #pragma unroll
  for (int i=0;i<32;i+=8){
    int r = r0+ty+i, c = c0+tx;
    float v = (c<Cin) ? in[(size_t)r*Cin + c] : 0.f;
    if (rs) v *= rs[r];
    t[ty+i][tx] = v;
  }
  __syncthreads();
  #pragma unroll
  for (int i=0;i<32;i+=8){
    int c = c0+ty+i, r = r0+tx;
    if (c < Cpad) out[(size_t)c*R + r] = f2bf(t[tx][ty+i]);
  }
}

// ---------------- bf16 MFMA GEMM 128x128, 2-phase dbuf prefetch ----------------
template<int MODE>
__global__ __launch_bounds__(256,2) void gemm_bf16(const unsigned short* __restrict__ A,
    const unsigned short* __restrict__ Bt, float* __restrict__ Cf,
    unsigned short* __restrict__ Cb, int Ntrue, int K, int ldc){
  __shared__ alignas(16) unsigned short As[2][128*32];
  __shared__ alignas(16) unsigned short Bs[2][128*32];
  int tid = threadIdx.x;
  int wave = tid >> 6, lane = tid & 63;
  int mBase = blockIdx.y*128, nBase = blockIdx.x*128;
  const size_t K2 = (size_t)K*2;
  int o0 = wave*1024 + lane*16;
  int o1 = o0 + 4096;
  const char* Ag0 = (const char*)A + (size_t)(mBase + (o0>>6))*K2 + (o0&63);
  const char* Ag1 = (const char*)A + (size_t)(mBase + (o1>>6))*K2 + (o1&63);
  const char* Bg0 = (const char*)Bt + (size_t)(nBase + (o0>>6))*K2 + (o0&63);
  const char* Bg1 = (const char*)Bt + (size_t)(nBase + (o1>>6))*K2 + (o1&63);

  int wm = (wave>>1)*64, wn = (wave&1)*64;
  int ln = lane & 15, quad = lane >> 4;

  f32x4 acc[4][4];
  #pragma unroll
  for (int i=0;i<4;i++)
    #pragma unroll
    for (int j=0;j<4;j++) acc[i][j] = (f32x4){0.f,0.f,0.f,0.f};

  auto stage = [&](int buf, int k0){
    size_t kb = (size_t)k0*2;
    char* AsW = (char*)(&As[buf][0]) + wave*1024;
    char* BsW = (char*)(&Bs[buf][0]) + wave*1024;
    load_lds16(Ag0 + kb, AsW);
    load_lds16(Ag1 + kb, AsW + 4096);
    load_lds16(Bg0 + kb, BsW);
    load_lds16(Bg1 + kb, BsW + 4096);
  };

  stage(0, 0);
  int cur = 0;
  for (int k0=0; k0<K; k0+=32){
    __syncthreads();                 // drains vmcnt: buf[cur] ready
    if (k0+32 < K) stage(cur^1, k0+32);  // prefetch overlaps MFMA below
    bf16x8 a[4], b[4];
    #pragma unroll
    for (int mt=0;mt<4;mt++)
      a[mt] = *(const bf16x8*)((const char*)(&As[cur][0]) + (size_t)(wm+mt*16+ln)*64 + quad*16);
    #pragma unroll
    for (int nt=0;nt<4;nt++)
      b[nt] = *(const bf16x8*)((const char*)(&Bs[cur][0]) + (size_t)(wn+nt*16+ln)*64 + quad*16);
    #pragma unroll
    for (int mt=0;mt<4;mt++)
      #pragma unroll
      for (int nt=0;nt<4;nt++)
        acc[mt][nt] = __builtin_amdgcn_mfma_f32_16x16x32_bf16(a[mt], b[nt], acc[mt][nt], 0,0,0);
    cur ^= 1;
  }

  #pragma unroll
  for (int mt=0;mt<4;mt++){
    #pragma unroll
    for (int nt=0;nt<4;nt++){
      int col = nBase + wn + nt*16 + ln;
      int row0 = mBase + wm + mt*16 + quad*4;
      if (col < Ntrue){
        #pragma unroll
        for (int r=0;r<4;r++){
          float v = acc[mt][nt][r];
          if (MODE==2) Cb[(size_t)(row0+r)*ldc + col] = f2bf(v);
          else         Cf[(size_t)(row0+r)*ldc + col] = v;
        }
      }
    }
  }
}

// ------ out-proj GEMM 64x64, BK=128, reg-staged 2-phase, fused rms row-scale ---
// C[row,:] += rsqrt(ss[row]/DI + eps) * (A @ Bt^T); gnw already folded into Bt.
__global__ __launch_bounds__(256,2) void gemm_out(const unsigned short* __restrict__ A,
    const unsigned short* __restrict__ Bt, const float* __restrict__ ssum,
    float* __restrict__ C, int N, int K){
  __shared__ alignas(16) unsigned short As[2][64*136];
  __shared__ alignas(16) unsigned short Bs[2][64*136];
  int tid = threadIdx.x;
  int wave = tid>>6, lane = tid&63, ln = lane&15, quad = lane>>4;
  int mBase = blockIdx.y*64, nBase = blockIdx.x*64;
  int srow = tid>>2, sseg = tid&3;
  const unsigned short* Ag = A + (size_t)(mBase+srow)*K;
  const unsigned short* Bg = Bt + (size_t)(nBase+srow)*K;

  bf16x8 rA[4], rB[4];
  auto ldregs = [&](int k0){
    #pragma unroll
    for (int s=0;s<4;s++){
      rA[s] = *(const bf16x8*)(Ag + k0 + (sseg+s*4)*8);
      rB[s] = *(const bf16x8*)(Bg + k0 + (sseg+s*4)*8);
    }
  };
  auto stlds = [&](int buf){
    #pragma unroll
    for (int s=0;s<4;s++){
      *(bf16x8*)&As[buf][srow*136 + (sseg+s*4)*8] = rA[s];
      *(bf16x8*)&Bs[buf][srow*136 + (sseg+s*4)*8] = rB[s];
    }
  };

  f32x4 acc[4];
  #pragma unroll
  for (int nt=0;nt<4;nt++) acc[nt] = (f32x4){0.f,0.f,0.f,0.f};

  ldregs(0); stlds(0);
  int cur = 0;
  for (int k0=0; k0<K; k0+=128){
    __syncthreads();                 // buf[cur] writes visible
    bool pf = (k0+128 < K);
    if (pf) ldregs(k0+128);          // loads overlap MFMA below
    bf16x8 a[4];
    #pragma unroll
    for (int kq=0;kq<4;kq++)
      a[kq] = *(const bf16x8*)&As[cur][(wave*16+ln)*136 + kq*32 + quad*8];
    #pragma unroll
    for (int nt=0;nt<4;nt++){
      #pragma unroll
      for (int kq=0;kq<4;kq++){
        bf16x8 b = *(const bf16x8*)&Bs[cur][(nt*16+ln)*136 + kq*32 + quad*8];
        acc[nt] = __builtin_amdgcn_mfma_f32_16x16x32_bf16(a[kq], b, acc[nt], 0,0,0);
      }
    }
    if (pf) stlds(cur^1);            // vmcnt wait lands here, after compute
    cur ^= 1;
  }
  int row0 = mBase + wave*16 + quad*4;
  #pragma unroll
  for (int r=0;r<4;r++){
    int row = row0 + r;
    float rsv = rsqrtf(ssum[row]*(1.f/DI) + EPSF);
    #pragma unroll
    for (int nt=0;nt<4;nt++){
      int col = nBase + nt*16 + ln;
      float* p = C + (size_t)row*N + col;
      *p += acc[nt][r]*rsv;
    }
  }
}

// ---------------- depthwise causal conv (K=4) + SiLU, vectorized x8 ------------
// also zeroes ssum[0..BATCH*SEQ) for this layer's gated-rms reduction
__global__ __launch_bounds__(256) void dwconv8(const unsigned short* __restrict__ zxb,
    const float* __restrict__ w, const float* __restrict__ bias,
    unsigned short* __restrict__ out, float* __restrict__ ssum){
  int idx = blockIdx.x*256+threadIdx.x;
  if (idx < BATCH*SEQ) ssum[idx] = 0.f;
  if (idx >= BATCH*SEQ*(CDIM/8)) return;
  int c8 = idx % (CDIM/8);
  int l  = (idx/(CDIM/8)) % SEQ;
  int b  = idx / ((CDIM/8)*SEQ);
  int c = c8*8;
  float acc[8];
  #pragma unroll
  for (int j=0;j<8;j++) acc[j] = bias[c+j];
  const unsigned short* colbase = zxb + (size_t)(b*SEQ)*PDIM + DI + c;
  #pragma unroll
  for (int k=0;k<4;k++){
    int li = l-3+k;
    if (li>=0){
      bf16x8 v = *(const bf16x8*)(colbase + (size_t)li*PDIM);
      #pragma unroll
      for (int j=0;j<8;j++) acc[j] += w[(c+j)*4+k]*bf2f((unsigned short)v[j]);
    }
  }
  unsigned short o[8];
  #pragma unroll
  for (int j=0;j<8;j++) o[j] = f2bf(siluf_(acc[j]));
  *(bf16x8*)(out + (size_t)idx*8) = *(bf16x8*)&o[0];
}

// ---------------- fused prep: dt cumsum + XdT/Xdec (blocks 0..191), BT (192..255)
__global__ __launch_bounds__(256) void prep_fused(const unsigned short* __restrict__ zxb,
    const unsigned short* __restrict__ xbcb,
    const float* __restrict__ dtb, const float* __restrict__ alog,
    float* __restrict__ acs, unsigned short* __restrict__ XdT,
    unsigned short* __restrict__ Xdec, unsigned short* __restrict__ BTg){
  int blk = blockIdx.x;
  int tid = threadIdx.x;
  __shared__ alignas(16) unsigned short Xs[64*72];
  __shared__ float dts[256];
  __shared__ float dec[256];
  __shared__ float wsum[4];
  if (blk < 192){
    int c = blk % NCH, h = (blk/NCH) % NH, b = blk/(NCH*NH);
    int bh = b*NH + h;
    // phase 1: dt + chunk cumsum (wave shfl scan, 1 barrier)
    int l = c*CHUNKC + tid;
    int lane = tid & 63, wv = tid >> 6;
    float negA = -expf(alog[h]);
    float lg = bf2f(zxb[((size_t)(b*SEQ+l))*PDIM + (DI+CDIM) + h]) + dtb[h];
    float dt = softplusf_(lg);
    dts[tid] = dt;
    float s = dt*negA;
    #pragma unroll
    for (int off=1; off<64; off<<=1){
      float t = __shfl_up(s, off, 64);
      if (lane >= off) s += t;
    }
    if (lane == 63) wsum[wv] = s;
    __syncthreads();
    float pre = 0.f, tot = 0.f;
    #pragma unroll
    for (int w=0; w<4; w++){
      float wv2 = wsum[w];
      if (w < wv) pre += wv2;
      tot += wv2;
    }
    s += pre;
    acs[(size_t)bh*SEQ + l] = s;
    dec[tid] = expf(tot - s);
    // phase 2: 4 subtiles of 64 rows -> XdT, Xdec
    int srow = tid>>2, sseg = tid&3;
    int p = tid>>2, lq = tid&3;
    for (int lt2=0; lt2<4; lt2++){
      int lt = c*4 + lt2;
      __syncthreads();
      const unsigned short* src = xbcb + ((size_t)(b*SEQ) + lt*64 + srow)*CDIM + h*HD;
      #pragma unroll
      for (int s2=0;s2<2;s2++)
        *(bf16x8*)&Xs[srow*72 + (sseg+s2*4)*8] = *(const bf16x8*)(src + (sseg+s2*4)*8);
      __syncthreads();
      unsigned short o1[16], o2[16];
      #pragma unroll
      for (int li=0; li<16; li++){
        int j = lq*16+li;            // row within subtile
        int lc = lt2*64 + j;         // index within chunk
        float vv = bf2f(Xs[j*72 + p]) * dts[lc];
        o1[li] = f2bf(vv);
        o2[li] = f2bf(vv*dec[lc]);
      }
      size_t rowo = ((size_t)bh*HD + p)*SEQ + lt*64 + lq*16;
      *(bf16x8*)(XdT + rowo)     = *(bf16x8*)&o1[0];
      *(bf16x8*)(XdT + rowo + 8) = *(bf16x8*)&o1[8];
      *(bf16x8*)(Xdec + rowo)     = *(bf16x8*)&o2[0];
      *(bf16x8*)(Xdec + rowo + 8) = *(bf16x8*)&o2[8];
    }
  } else {
    int r = blk - 192;
    int nh = r & 1, lt = (r>>1) & 15, b = r >> 5;
    int srow = tid>>2, sseg = tid&3;
    const unsigned short* src = xbcb + ((size_t)(b*SEQ) + lt*64 + srow)*CDIM + DI + nh*64;
    #pragma unroll
    for (int s2=0;s2<2;s2++)
      *(bf16x8*)&Xs[srow*72 + (sseg+s2*4)*8] = *(const bf16x8*)(src + (sseg+s2*4)*8);
    __syncthreads();
    int n = tid>>2, lq = tid&3;
    unsigned short o[16];
    #pragma unroll
    for (int li=0; li<16; li++) o[li] = Xs[(lq*16+li)*72 + n];
    size_t rowo = ((size_t)b*DSTATE + nh*64 + n)*SEQ + lt*64 + lq*16;
    *(bf16x8*)(BTg + rowo)     = *(bf16x8*)&o[0];
    *(bf16x8*)(BTg + rowo + 8) = *(bf16x8*)&o[8];
  }
}

// ---------------- SSD chunk states: D[p=64][n=64] = Xdec[p][:] . BT[n][:]^T ----
__global__ __launch_bounds__(256) void ssd_states2(const unsigned short* __restrict__ Xdec,
    const unsigned short* __restrict__ BTg, float* __restrict__ states){
  int blk = blockIdx.x;
  int nh = blk & 1;
  int r = blk >> 1;
  int h = r % NH;  r /= NH;
  int c = r % NCH;
  int b = r / NCH;
  int tid = threadIdx.x, wave = tid>>6, lane = tid&63, ln = lane&15, quad = lane>>4;
  __shared__ alignas(16) unsigned short As[64*264];
  __shared__ alignas(16) unsigned short Bs[64*264];
  int bh = b*NH + h;
  {
    int srow = tid>>2, sseg = tid&3;
    const unsigned short* ga = Xdec + ((size_t)bh*HD + srow)*SEQ + c*CHUNKC;
    const unsigned short* gb = BTg + ((size_t)b*DSTATE + nh*64 + srow)*SEQ + c*CHUNKC;
    #pragma unroll
    for (int s=0;s<8;s++){
      *(bf16x8*)&As[srow*264 + (sseg+s*4)*8] = *(const bf16x8*)(ga + (sseg+s*4)*8);
      *(bf16x8*)&Bs[srow*264 + (sseg+s*4)*8] = *(const bf16x8*)(gb + (sseg+s*4)*8);
    }
  }
  __syncthreads();
  f32x4 acc[4];
  #pragma unroll
  for (int nt=0;nt<4;nt++) acc[nt] = (f32x4){0.f,0.f,0.f,0.f};
  bf16x8 a[8];
  #pragma unroll
  for (int kq=0;kq<8;kq++)
    a[kq] = *(const bf16x8*)&As[(wave*16+ln)*264 + kq*32 + quad*8];
  #pragma unroll
  for (int nt=0;nt<4;nt++){
    #pragma unroll
    for (int kq=0;kq<8;kq++){
      bf16x8 bb = *(const bf16x8*)&Bs[(nt*16+ln)*264 + kq*32 + quad*8];
      acc[nt] = __builtin_amdgcn_mfma_f32_16x16x32_bf16(a[kq], bb, acc[nt], 0,0,0);
    }
  }
  float* sp = states + (((size_t)(b*NCH+c)*NH + h) << 13) + nh*64;
  #pragma unroll
  for (int nt=0;nt<4;nt++){
    #pragma unroll
    for (int r2=0;r2<4;r2++)
      sp[(size_t)(wave*16 + quad*4 + r2)*DSTATE + nt*16 + ln] = acc[nt][r2];
  }
}

// ---------------- inter-chunk scan (prev stored bf16) ----------------
__global__ __launch_bounds__(256) void ssd_scan(const float* __restrict__ states,
    const float* __restrict__ acs, unsigned short* __restrict__ prev){
  int idx = blockIdx.x*256+threadIdx.x;
  if (idx >= BATCH*NH*HD*DSTATE) return;
  int pn = idx & 8191;
  int bh = idx >> 13;
  int h = bh % NH, b = bh / NH;
  float carry = 0.f;
  #pragma unroll
  for (int c=0;c<NCH;c++){
    size_t o = (((size_t)(b*NCH+c)*NH + h) << 13) + pn;
    prev[o] = f2bf(carry);
    float dec = expf(acs[(b*NH+h)*SEQ + c*CHUNKC + CHUNKC-1]);
    carry = carry*dec + states[o];
  }
}

// ---------------- SSD diag + off-diag + skip + gate/silu + ss reduce -----------
constexpr int CW_S  = 136;
constexpr int SB_S  = 72;
constexpr int XT_S  = 72;

__global__ __launch_bounds__(256,2) void ssd_diag2(
    const unsigned short* __restrict__ xbcb, const unsigned short* __restrict__ XdT,
    const float* __restrict__ acs, const unsigned short* __restrict__ prev,
    const float* __restrict__ dskip, const unsigned short* __restrict__ zxb,
    float* __restrict__ ssum, unsigned short* __restrict__ Y){
  int blk = blockIdx.x;
  int t = blk & 3;
  int r0 = blk >> 2;
  int h = r0 % NH;  r0 /= NH;
  int c = r0 % NCH;
  int b = r0 / NCH;

  int tid = threadIdx.x;
  int wave = tid>>6, lane = tid&63, ln = lane&15, quad = lane>>4;

  __shared__ float ac[CHUNKC];
  __shared__ alignas(16) unsigned short Cw[64*CW_S];
  __shared__ alignas(16) unsigned short Pv[64*CW_S];
  __shared__ alignas(16) unsigned short Bt[64*CW_S];
  __shared__ alignas(16) unsigned short Xt[64*XT_S];
  __shared__ alignas(16) unsigned short Sb[4][16*SB_S];

  const int bh = b*NH + h;
  const size_t rowbase = (size_t)(b*SEQ + c*CHUNKC);

  ac[tid] = acs[(size_t)bh*SEQ + c*CHUNKC + tid];

  {
    int srow = tid>>2, sseg = tid&3;
    const unsigned short* gc = xbcb + (rowbase + t*64 + srow)*CDIM + DI + DSTATE;
    const unsigned short* gp = prev + (((size_t)(b*NCH+c)*NH + h) << 13) + (size_t)srow*DSTATE;
    #pragma unroll
    for (int s=0;s<4;s++){
      *(bf16x8*)&Cw[srow*CW_S + (sseg+s*4)*8] = *(const bf16x8*)(gc + (sseg+s*4)*8);
      *(bf16x8*)&Pv[srow*CW_S + (sseg+s*4)*8] = *(const bf16x8*)(gp + (sseg+s*4)*8);
    }
  }
  __syncthreads();

  bf16x8 aC[4];
  #pragma unroll
  for (int kq=0;kq<4;kq++)
    aC[kq] = *(const bf16x8*)&Cw[(wave*16+ln)*CW_S + kq*32 + quad*8];

  f32x4 yacc[4];
  #pragma unroll
  for (int ps=0;ps<4;ps++) yacc[ps] = (f32x4){0.f,0.f,0.f,0.f};

  for (int jt=0; jt<=t; jt++){
    __syncthreads();
    {
      int srow = tid>>2, sseg = tid&3;
      const unsigned short* gbm = xbcb + (rowbase + jt*64 + srow)*CDIM + DI;
      #pragma unroll
      for (int s=0;s<4;s++)
        *(bf16x8*)&Bt[srow*CW_S + (sseg+s*4)*8] = *(const bf16x8*)(gbm + (sseg+s*4)*8);
      const unsigned short* gx = XdT + ((size_t)bh*HD + srow)*SEQ + c*CHUNKC + jt*64;
      #pragma unroll
      for (int s=0;s<2;s++)
        *(bf16x8*)&Xt[srow*XT_S + (sseg+s*4)*8] = *(const bf16x8*)(gx + (sseg+s*4)*8);
    }
    __syncthreads();

    #pragma unroll
    for (int js=0; js<4; js++){
      f32x4 s = (f32x4){0.f,0.f,0.f,0.f};
      #pragma unroll
      for (int kq=0;kq<4;kq++){
        bf16x8 bB = *(const bf16x8*)&Bt[(js*16+ln)*CW_S + kq*32 + quad*8];
        s = __builtin_amdgcn_mfma_f32_16x16x32_bf16(aC[kq], bB, s, 0,0,0);
      }
      int jc = jt*64 + js*16 + ln;
      #pragma unroll
      for (int r=0;r<4;r++){
        int icl = t*64 + wave*16 + quad*4 + r;
        float d = (jc<=icl) ? (ac[icl]-ac[jc]) : -1e30f;
        Sb[wave][(quad*4+r)*SB_S + js*16 + ln] = f2bf(expf(d)*s[r]);
      }
    }
    bf16x8 aS[2];
    #pragma unroll
    for (int kq=0;kq<2;kq++)
      aS[kq] = *(const bf16x8*)&Sb[wave][ln*SB_S + kq*32 + quad*8];
    #pragma unroll
    for (int ps=0;ps<4;ps++){
      #pragma unroll
      for (int kq=0;kq<2;kq++){
        bf16x8 bX = *(const bf16x8*)&Xt[(ps*16+ln)*XT_S + kq*32 + quad*8];
        yacc[ps] = __builtin_amdgcn_mfma_f32_16x16x32_bf16(aS[kq], bX, yacc[ps], 0,0,0);
      }
    }
  }

  f32x4 oacc[4];
  #pragma unroll
  for (int ps=0;ps<4;ps++) oacc[ps] = (f32x4){0.f,0.f,0.f,0.f};
  #pragma unroll
  for (int ps=0;ps<4;ps++){
    #pragma unroll
    for (int kq=0;kq<4;kq++){
      bf16x8 bP = *(const bf16x8*)&Pv[(ps*16+ln)*CW_S + kq*32 + quad*8];
      oacc[ps] = __builtin_amdgcn_mfma_f32_16x16x32_bf16(aC[kq], bP, oacc[ps], 0,0,0);
    }
  }

  float dsk = dskip[h];
  #pragma unroll
  for (int r=0;r<4;r++){
    int icl = t*64 + wave*16 + quad*4 + r;
    float ei = expf(ac[icl]);
    size_t l = rowbase + icl;
    float rss = 0.f;
    #pragma unroll
    for (int ps=0;ps<4;ps++){
      int p = ps*16 + ln;
      float xraw = bf2f(xbcb[l*CDIM + h*HD + p]);
      float zv = bf2f(zxb[l*PDIM + h*HD + p]);
      float yg = (yacc[ps][r] + ei*oacc[ps][r] + dsk*xraw) * siluf_(zv);
      Y[l*DI + h*HD + p] = f2bf(yg);
      rss += yg*yg;
    }
    // reduce over the 16 lanes of this quad (aligned 16-lane group)
    rss += __shfl_down(rss, 8, 64);
    rss += __shfl_down(rss, 4, 64);
    rss += __shfl_down(rss, 2, 64);
    rss += __shfl_down(rss, 1, 64);
    if (ln == 0) atomicAdd(&ssum[l], rss);
  }
}

// ---------------- final pooling + head -----------------------------------------
__global__ __launch_bounds__(256) void mean_pool(const float* __restrict__ hn,
    float* __restrict__ pooled){
  int idx = blockIdx.x*256+threadIdx.x;
  if (idx >= BATCH*DM) return;
  int b = idx / DM, d = idx % DM;
  float s = 0.f;
  for (int l=0;l<SEQ;l++) s += hn[((size_t)(b*SEQ+l))*DM + d];
  pooled[idx] = s * (1.f/SEQ);
}

__global__ __launch_bounds__(512) void head_k(const float* __restrict__ pooled,
    const float* __restrict__ w1, const float* __restrict__ b1,
    const float* __restrict__ g, const float* __restrict__ bb,
    const float* __restrict__ mn, const float* __restrict__ vr,
    const float* __restrict__ w2, const float* __restrict__ b2,
    float* __restrict__ out){
  int b = blockIdx.x;
  int j = threadIdx.x;
  __shared__ float f[512];
  __shared__ float pl[DM];
  for (int t=j; t<DM; t+=512) pl[t] = pooled[b*DM+t];
  __syncthreads();
  float s = b1[j];
  for (int k=0;k<DM;k++) s += pl[k]*w1[k*512+j];
  s = (s-mn[j])*(g[j]*rsqrtf(vr[j]+EPSF)) + bb[j];
  f[j] = fmaxf(s,0.f);
  __syncthreads();
  if (j < 27){
    float o = b2[j];
    for (int k=0;k<512;k++) o += f[k]*w2[k*27+j];
    out[b*27+j] = o;
  }
}

extern "C" void kernel_launch(void* const* d_in, const int* in_sizes, int n_in,
                              void* d_out, int out_size, void* d_ws, size_t ws_size,
                              hipStream_t stream){
  const float* x      = (const float*)d_in[0];
  const float* c1_w   = (const float*)d_in[1];
  const float* c1_b   = (const float*)d_in[2];
  const float* bn1_g  = (const float*)d_in[3];
  const float* bn1_b  = (const float*)d_in[4];
  const float* bn1_m  = (const float*)d_in[5];
  const float* bn1_v  = (const float*)d_in[6];
  const float* c2_w   = (const float*)d_in[7];
  const float* c2_b   = (const float*)d_in[8];
  const float* bn2_g  = (const float*)d_in[9];
  const float* bn2_b  = (const float*)d_in[10];
  const float* bn2_m  = (const float*)d_in[11];
  const float* bn2_v  = (const float*)d_in[12];
  const float* c3_w   = (const float*)d_in[13];
  const float* c3_b   = (const float*)d_in[14];
  const float* bn3_g  = (const float*)d_in[15];
  const float* bn3_b  = (const float*)d_in[16];
  const float* bn3_m  = (const float*)d_in[17];
  const float* bn3_v  = (const float*)d_in[18];
  const float* ln_w   = (const float*)d_in[19];
  const float* inpw   = (const float*)d_in[20];
  const float* convw  = (const float*)d_in[21];
  const float* convb  = (const float*)d_in[22];
  const float* dtb    = (const float*)d_in[23];
  const float* alog   = (const float*)d_in[24];
  const float* dskip  = (const float*)d_in[25];
  const float* gnw    = (const float*)d_in[26];
  const float* outw   = (const float*)d_in[27];
  const float* normfw = (const float*)d_in[28];
  const float* fc1w   = (const float*)d_in[29];
  const float* fc1b   = (const float*)d_in[30];
  const float* bncg   = (const float*)d_in[31];
  const float* bncb   = (const float*)d_in[32];
  const float* bncm   = (const float*)d_in[33];
  const float* bncv   = (const float*)d_in[34];
  const float* fc2w   = (const float*)d_in[35];
  const float* fc2b   = (const float*)d_in[36];
  (void)in_sizes; (void)n_in; (void)out_size;

  char* ws = (char*)d_ws;
  size_t off = 0;
  auto alloc = [&](size_t bytes){
    char* p = ws + off;
    off += (bytes + 255) & ~(size_t)255;
    return (void*)p;
  };
  float* h1  = (float*)alloc((size_t)BATCH*192*LS1*4);
  float* h2  = (float*)alloc((size_t)BATCH*384*LS2*4);
  float* h   = (float*)alloc((size_t)BATCH*SEQ*DM*4);
  float* hn  = (float*)alloc((size_t)BATCH*SEQ*DM*4);
  unsigned short* zxb = (unsigned short*)alloc((size_t)BATCH*SEQ*PDIM*2);
  unsigned short* xbcb= (unsigned short*)alloc((size_t)BATCH*SEQ*CDIM*2);
  float* acs = (float*)alloc((size_t)BATCH*NH*SEQ*4);
  float* st  = (float*)alloc((size_t)BATCH*NCH*NH*HD*DSTATE*4);
  unsigned short* pv  = (unsigned short*)alloc((size_t)BATCH*NCH*NH*HD*DSTATE*2);
  unsigned short* Y   = (unsigned short*)alloc((size_t)BATCH*SEQ*DI*2);
  float* pooled = (float*)alloc((size_t)BATCH*DM*4);
  unsigned short* hnb   = (unsigned short*)alloc((size_t)BATCH*SEQ*DM*2);
  float* ssum = (float*)alloc((size_t)BATCH*SEQ*4);
  unsigned short* XdTg  = (unsigned short*)alloc((size_t)BATCH*NH*HD*SEQ*2);
  unsigned short* Xdecg = (unsigned short*)alloc((size_t)BATCH*NH*HD*SEQ*2);
  unsigned short* BTg   = (unsigned short*)alloc((size_t)BATCH*DSTATE*SEQ*2);

  // weight buffers: all-layer (hoisted) if ws allows, else per-layer fallback
  const size_t wtin_l  = (size_t)PPAD*DM;     // elems per layer
  const size_t wtout_l = (size_t)DM*DI;
  size_t base_off = off;
  size_t big_bytes = (wtin_l + wtout_l)*NLAYER*2 + 512;
  bool big = (ws_size >= base_off + big_bytes);
  unsigned short *wtinA, *wtoutA;
  if (big){
    wtinA  = (unsigned short*)alloc(wtin_l*NLAYER*2);
    wtoutA = (unsigned short*)alloc(wtout_l*NLAYER*2);
  } else {
    wtinA  = (unsigned short*)alloc(wtin_l*2);
    wtoutA = (unsigned short*)alloc(wtout_l*2);
  }

  if (big){
    transpose_cvt_l<<<dim3(PPAD/32, DM/32, NLAYER),256,0,stream>>>(
        inpw, wtinA, DM, PDIM, PPAD, (size_t)DM*PDIM, wtin_l, nullptr, 0);
    // fold gnw into out_proj weight (rms column weight is the GEMM K dim)
    transpose_cvt_l<<<dim3(DM/32, DI/32, NLAYER),256,0,stream>>>(
        outw, wtoutA, DI, DM, DM, (size_t)DI*DM, wtout_l, gnw, (size_t)DI);
  }

  conv_stem1<<<(BATCH*192*LS1+255)/256,256,0,stream>>>(x, c1_w,c1_b, bn1_g,bn1_b,bn1_m,bn1_v, h1);
  conv_stem2<<<(BATCH*384*LS2+255)/256,256,0,stream>>>(h1, c2_w,c2_b, bn2_g,bn2_b,bn2_m,bn2_v, h2);
  conv_stem3<<<BATCH*768,256,0,stream>>>(h2, c3_w,c3_b, bn3_g,bn3_b,bn3_m,bn3_v, h);

  const int M = BATCH*SEQ;  // 2048
  for (int l=0; l<NLAYER; l++){
    unsigned short* wtin  = big ? (wtinA  + (size_t)l*wtin_l)  : wtinA;
    unsigned short* wtout = big ? (wtoutA + (size_t)l*wtout_l) : wtoutA;
    if (!big){
      transpose_cvt_l<<<dim3(PPAD/32, DM/32, 1),256,0,stream>>>(
          inpw + (size_t)l*DM*PDIM, wtin, DM, PDIM, PPAD, 0, 0, nullptr, 0);
      transpose_cvt_l<<<dim3(DM/32, DI/32, 1),256,0,stream>>>(
          outw + (size_t)l*DI*DM, wtout, DI, DM, DM, 0, 0, gnw + (size_t)l*DI, 0);
    }

    rmsnorm768<1><<<M,256,0,stream>>>(h, ln_w + (size_t)l*DM, nullptr, hnb);
    gemm_bf16<2><<<dim3(PPAD/128, M/128),256,0,stream>>>(hnb, wtin, nullptr, zxb, PDIM, DM, PDIM);
    dwconv8<<<(BATCH*SEQ*(CDIM/8)+255)/256,256,0,stream>>>(zxb, convw + (size_t)l*CDIM*4, convb + (size_t)l*CDIM, xbcb, ssum);
    prep_fused<<<256,256,0,stream>>>(zxb, xbcb, dtb + l*NH, alog + l*NH, acs, XdTg, Xdecg, BTg);
    ssd_states2<<<BATCH*NCH*NH*2,256,0,stream>>>(Xdecg, BTg, st);
    ssd_scan<<<(BATCH*NH*HD*DSTATE+255)/256,256,0,stream>>>(st, acs, pv);
    ssd_diag2<<<BATCH*NCH*NH*4,256,0,stream>>>(xbcb, XdTg, acs, pv, dskip + l*NH, zxb, ssum, Y);
    gemm_out<<<dim3(DM/64, M/64),256,0,stream>>>(Y, wtout, ssum, h, DM, DI);
  }

  rmsnorm768<0><<<M,256,0,stream>>>(h, normfw, hn, nullptr);
  mean_pool<<<(BATCH*DM+255)/256,256,0,stream>>>(hn, pooled);
  head_k<<<BATCH,512,0,stream>>>(pooled, fc1w, fc1b, bncg,bncb,bncm,bncv, fc2w, fc2b, (float*)d_out);
}

// Round 2
// 3754.918 us; speedup vs baseline: 1.1746x; 1.1509x over previous
//
#include <hip/hip_runtime.h>
#include <math.h>

#define DEV __device__ __forceinline__

constexpr int BATCH = 2;
constexpr int L0 = 4096;
constexpr int LS1 = 2048;
constexpr int LS2 = 1024;
constexpr int SEQ = 1024;
constexpr int DM = 768;
constexpr int NH = 24;
constexpr int HD = 64;
constexpr int DI = 1536;
constexpr int DSTATE = 128;
constexpr int CDIM = 1792;   // DI + 2*DSTATE
constexpr int PDIM = 3352;   // 2*DI + 2*DSTATE + NH
constexpr int PPAD = 3456;   // PDIM padded to 27*128
constexpr int CHUNKC = 256;
constexpr int NCH = 4;
constexpr int NLAYER = 24;
constexpr float EPSF = 1e-5f;

// padded transposed stem buffers
constexpr int XT2_ROWS = 2050;             // l=-1..2048 (row = l+1)
constexpr size_t XT2_BSTRIDE = (size_t)XT2_ROWS*192;
constexpr int XT3_ROWS = 1026;             // l=-1..1024 (row = l+1)
constexpr size_t XT3_BSTRIDE = (size_t)XT3_ROWS*384;

typedef short bf16x8 __attribute__((ext_vector_type(8)));
typedef float f32x4 __attribute__((ext_vector_type(4)));

DEV float sigmoidf_(float x){ return 1.f/(1.f+expf(-x)); }
DEV float siluf_(float x){ return x*sigmoidf_(x); }
DEV float geluf_(float x){ return 0.5f*x*(1.f+erff(x*0.70710678118654752440f)); }
DEV float softplusf_(float x){ return fmaxf(x,0.f) + log1pf(expf(-fabsf(x))); }

DEV unsigned short f2bf(float x){
  union { float f; unsigned int u; } v; v.f = x;
  unsigned int u = v.u;
  unsigned int r = (u + 0x7fffu + ((u>>16)&1u)) >> 16;
  return (unsigned short)r;
}
DEV float bf2f(unsigned short u){
  union { unsigned int u; float f; } v; v.u = ((unsigned int)u)<<16; return v.f;
}

DEV void load_lds16(const void* g, void* l){
  __builtin_amdgcn_global_load_lds(
      (const __attribute__((address_space(1))) unsigned int*)g,
      (__attribute__((address_space(3))) unsigned int*)l,
      16, 0, 0);
}

DEV float block_sum_256(float v, float* red4){
  #pragma unroll
  for (int o=32;o>0;o>>=1) v += __shfl_down(v,o,64);
  int tid = threadIdx.x;
  __syncthreads();
  if ((tid&63)==0) red4[tid>>6]=v;
  __syncthreads();
  return red4[0]+red4[1]+red4[2]+red4[3];
}

// ---------------- stem1 (fp32, small K) ----------------
__global__ __launch_bounds__(256) void conv_stem1(const float* __restrict__ x,
    const float* __restrict__ w, const float* __restrict__ bias,
    const float* __restrict__ g, const float* __restrict__ bb,
    const float* __restrict__ mn, const float* __restrict__ vr,
    float* __restrict__ out){
  int idx = blockIdx.x*256+threadIdx.x;
  if (idx >= BATCH*192*LS1) return;
  int lo = idx & (LS1-1);
  int co = (idx >> 11) % 192;
  int b  = idx / (192*LS1);
  float s = bias[co];
  const float* wr = w + co*60;
  #pragma unroll
  for (int ci=0; ci<12; ci++){
    const float* xr = x + ((size_t)(b*12+ci))*L0;
    #pragma unroll
    for (int k=0;k<5;k++){
      int li = lo*2 + k - 2;
      if (li>=0 && li<L0) s += wr[ci*5+k]*xr[li];
    }
  }
  s = geluf_(s);
  s = (s-mn[co])*(g[co]*rsqrtf(vr[co]+EPSF)) + bb[co];
  out[idx] = s;
}

// ---- stem weight reorder: w[co][ci][k] fp32 -> wt[co][k*CI+ci] bf16 ----
__global__ __launch_bounds__(256) void wt_reorder(const float* __restrict__ w,
    unsigned short* __restrict__ o, int CO, int CI, int KK){
  int idx = blockIdx.x*256+threadIdx.x;
  if (idx >= CO*CI*KK) return;
  int ci = idx % CI;
  int k  = (idx/CI) % KK;
  int co = idx/(CI*KK);
  o[idx] = f2bf(w[(size_t)co*CI*KK + (size_t)ci*KK + k]);
}

// ---- transpose fp32 [R][C] (per batch) -> bf16 padded [C+2][R], row=c+1 ----
__global__ __launch_bounds__(256) void transpose_pad_bf(const float* __restrict__ in,
    unsigned short* __restrict__ out, int R, int C,
    size_t in_bstride, size_t out_bstride){
  const float* ib = in + (size_t)blockIdx.z*in_bstride;
  unsigned short* ob = out + (size_t)blockIdx.z*out_bstride;
  __shared__ float t[32][33];
  int c0 = blockIdx.x*32, r0 = blockIdx.y*32;
  int tx = threadIdx.x & 31, ty = threadIdx.x >> 5;
  #pragma unroll
  for (int i=0;i<32;i+=8)
    t[ty+i][tx] = ib[(size_t)(r0+ty+i)*C + c0+tx];
  __syncthreads();
  #pragma unroll
  for (int i=0;i<32;i+=8)
    ob[(size_t)(c0+ty+i+1)*R + r0+tx] = f2bf(t[tx][ty+i]);
  if (blockIdx.x==0 && ty==0){
    ob[r0+tx] = 0;
    ob[(size_t)(C+1)*R + r0+tx] = 0;
  }
}

// ---- zero pad rows of xT3 (rows 0 and 1025, both batches) ----
__global__ __launch_bounds__(256) void zero_rows3(unsigned short* __restrict__ xT3){
  int i = blockIdx.x*256+threadIdx.x;
  if (i >= 2*2*384) return;
  int ci = i % 384;
  int r  = (i/384) & 1;
  int b2 = i / 768;
  xT3[(size_t)b2*XT3_BSTRIDE + (size_t)(r?1025:0)*384 + ci] = 0;
}

// ---- implicit-GEMM stem conv: A = overlapping windows of padded xT ----
// MODE 0: stem2 -> bf16 into padded xT3 (row lo+1); MODE 1: stem3 -> fp32 h
template<int MODE>
__global__ __launch_bounds__(256,2) void gemm_stem(const unsigned short* __restrict__ A,
    const unsigned short* __restrict__ Bt,
    const float* __restrict__ bias, const float* __restrict__ g,
    const float* __restrict__ bbn, const float* __restrict__ mn,
    const float* __restrict__ vr,
    unsigned short* __restrict__ Ob, float* __restrict__ Of,
    int K, int rowStride, size_t batchStride){
  __shared__ alignas(16) unsigned short As[2][128*32];
  __shared__ alignas(16) unsigned short Bs[2][128*32];
  int tid = threadIdx.x;
  int wave = tid >> 6, lane = tid & 63;
  int mBase = blockIdx.y*128, nBase = blockIdx.x*128;
  int bidx = mBase >> 10;            // rows per batch = 1024
  int mloc = mBase & 1023;
  const unsigned short* Ab = A + (size_t)bidx*batchStride + (size_t)mloc*rowStride;
  const size_t rs2 = (size_t)rowStride*2;
  const size_t K2 = (size_t)K*2;
  int o0 = wave*1024 + lane*16;
  int o1 = o0 + 4096;
  const char* Ag0 = (const char*)Ab + (size_t)(o0>>6)*rs2 + (o0&63);
  const char* Ag1 = (const char*)Ab + (size_t)(o1>>6)*rs2 + (o1&63);
  const char* Bg0 = (const char*)Bt + (size_t)(nBase + (o0>>6))*K2 + (o0&63);
  const char* Bg1 = (const char*)Bt + (size_t)(nBase + (o1>>6))*K2 + (o1&63);

  int wm = (wave>>1)*64, wn = (wave&1)*64;
  int ln = lane & 15, quad = lane >> 4;

  f32x4 acc[4][4];
  #pragma unroll
  for (int i=0;i<4;i++)
    #pragma unroll
    for (int j=0;j<4;j++) acc[i][j] = (f32x4){0.f,0.f,0.f,0.f};

  auto stage = [&](int buf, int k0){
    size_t kb = (size_t)k0*2;
    char* AsW = (char*)(&As[buf][0]) + wave*1024;
    char* BsW = (char*)(&Bs[buf][0]) + wave*1024;
    load_lds16(Ag0 + kb, AsW);
    load_lds16(Ag1 + kb, AsW + 4096);
    load_lds16(Bg0 + kb, BsW);
    load_lds16(Bg1 + kb, BsW + 4096);
  };

  stage(0, 0);
  int cur = 0;
  for (int k0=0; k0<K; k0+=32){
    __syncthreads();
    if (k0+32 < K) stage(cur^1, k0+32);
    bf16x8 a[4], b[4];
    #pragma unroll
    for (int mt=0;mt<4;mt++)
      a[mt] = *(const bf16x8*)((const char*)(&As[cur][0]) + (size_t)(wm+mt*16+ln)*64 + quad*16);
    #pragma unroll
    for (int nt=0;nt<4;nt++)
      b[nt] = *(const bf16x8*)((const char*)(&Bs[cur][0]) + (size_t)(wn+nt*16+ln)*64 + quad*16);
    #pragma unroll
    for (int mt=0;mt<4;mt++)
      #pragma unroll
      for (int nt=0;nt<4;nt++)
        acc[mt][nt] = __builtin_amdgcn_mfma_f32_16x16x32_bf16(a[mt], b[nt], acc[mt][nt], 0,0,0);
    cur ^= 1;
  }

  #pragma unroll
  for (int nt=0;nt<4;nt++){
    int col = nBase + wn + nt*16 + ln;
    float bs = bias[col];
    float sc = g[col]*rsqrtf(vr[col]+EPSF);
    float bnm2 = mn[col], bnb2 = bbn[col];
    #pragma unroll
    for (int mt=0;mt<4;mt++){
      int row0 = mBase + wm + mt*16 + quad*4;
      #pragma unroll
      for (int r=0;r<4;r++){
        int row = row0 + r;
        float v = acc[mt][nt][r] + bs;
        v = geluf_(v);
        v = (v-bnm2)*sc + bnb2;
        if (MODE==0){
          int b2 = row >> 10, lr = row & 1023;
          Ob[(size_t)b2*XT3_BSTRIDE + (size_t)(lr+1)*384 + col] = f2bf(v);
        } else {
          Of[(size_t)row*DM + col] = v;
        }
      }
    }
  }
}

// ---------------- rmsnorm (D=768) ----------------
template<int BF>
__global__ __launch_bounds__(256) void rmsnorm768(const float* __restrict__ in,
    const float* __restrict__ w, float* __restrict__ outf, unsigned short* __restrict__ outb){
  int row = blockIdx.x;
  const float* p = in + (size_t)row*DM;
  float v0[3]; float ss=0.f;
  #pragma unroll
  for (int t=0;t<3;t++){ float q = p[threadIdx.x + t*256]; v0[t]=q; ss+=q*q; }
  __shared__ float red[4];
  float tot = block_sum_256(ss, red);
  float sc = rsqrtf(tot*(1.f/DM) + EPSF);
  #pragma unroll
  for (int t=0;t<3;t++){
    int d = threadIdx.x + t*256;
    float o = v0[t]*sc*w[d];
    if (BF) outb[(size_t)row*DM + d] = f2bf(o);
    else    outf[(size_t)row*DM + d] = o;
  }
}

// ------- transpose + fp32->bf16, batched over layers via blockIdx.z ------------
// rsc: optional per-input-row scale (used to fold gnw into out_proj weight)
__global__ __launch_bounds__(256) void transpose_cvt_l(const float* __restrict__ in0,
    unsigned short* __restrict__ out0, int R, int Cin, int Cpad,
    size_t in_lstride, size_t out_lstride,
    const float* __restrict__ rsc, size_t rsc_stride){
  const float* in = in0 + (size_t)blockIdx.z*in_lstride;
  unsigned short* out = out0 + (size_t)blockIdx.z*out_lstride;
  const float* rs = rsc ? (rsc + (size_t)blockIdx.z*rsc_stride) : nullptr;
  __shared__ float t[32][33];
  int c0 = blockIdx.x*32, r0 = blockIdx.y*32;
  int tx = threadIdx.x & 31, ty = threadIdx.x >> 5;
  #pragma unroll
  for (int i=0;i<32;i+=8){
    int r = r0+ty+i, c = c0+tx;
    float v = (c<Cin) ? in[(size_t)r*Cin + c] : 0.f;
    if (rs) v *= rs[r];
    t[ty+i][tx] = v;
  }
  __syncthreads();
  #pragma unroll
  for (int i=0;i<32;i+=8){
    int c = c0+ty+i, r = r0+tx;
    if (c < Cpad) out[(size_t)c*R + r] = f2bf(t[tx][ty+i]);
  }
}

// ---------------- bf16 MFMA GEMM 128x128, 2-phase dbuf prefetch ----------------
template<int MODE>
__global__ __launch_bounds__(256,2) void gemm_bf16(const unsigned short* __restrict__ A,
    const unsigned short* __restrict__ Bt, float* __restrict__ Cf,
    unsigned short* __restrict__ Cb, int Ntrue, int K, int ldc){
  __shared__ alignas(16) unsigned short As[2][128*32];
  __shared__ alignas(16) unsigned short Bs[2][128*32];
  int tid = threadIdx.x;
  int wave = tid >> 6, lane = tid & 63;
  int mBase = blockIdx.y*128, nBase = blockIdx.x*128;
  const size_t K2 = (size_t)K*2;
  int o0 = wave*1024 + lane*16;
  int o1 = o0 + 4096;
  const char* Ag0 = (const char*)A + (size_t)(mBase + (o0>>6))*K2 + (o0&63);
  const char* Ag1 = (const char*)A + (size_t)(mBase + (o1>>6))*K2 + (o1&63);
  const char* Bg0 = (const char*)Bt + (size_t)(nBase + (o0>>6))*K2 + (o0&63);
  const char* Bg1 = (const char*)Bt + (size_t)(nBase + (o1>>6))*K2 + (o1&63);

  int wm = (wave>>1)*64, wn = (wave&1)*64;
  int ln = lane & 15, quad = lane >> 4;

  f32x4 acc[4][4];
  #pragma unroll
  for (int i=0;i<4;i++)
    #pragma unroll
    for (int j=0;j<4;j++) acc[i][j] = (f32x4){0.f,0.f,0.f,0.f};

  auto stage = [&](int buf, int k0){
    size_t kb = (size_t)k0*2;
    char* AsW = (char*)(&As[buf][0]) + wave*1024;
    char* BsW = (char*)(&Bs[buf][0]) + wave*1024;
    load_lds16(Ag0 + kb, AsW);
    load_lds16(Ag1 + kb, AsW + 4096);
    load_lds16(Bg0 + kb, BsW);
    load_lds16(Bg1 + kb, BsW + 4096);
  };

  stage(0, 0);
  int cur = 0;
  for (int k0=0; k0<K; k0+=32){
    __syncthreads();                 // drains vmcnt: buf[cur] ready
    if (k0+32 < K) stage(cur^1, k0+32);  // prefetch overlaps MFMA below
    bf16x8 a[4], b[4];
    #pragma unroll
    for (int mt=0;mt<4;mt++)
      a[mt] = *(const bf16x8*)((const char*)(&As[cur][0]) + (size_t)(wm+mt*16+ln)*64 + quad*16);
    #pragma unroll
    for (int nt=0;nt<4;nt++)
      b[nt] = *(const bf16x8*)((const char*)(&Bs[cur][0]) + (size_t)(wn+nt*16+ln)*64 + quad*16);
    #pragma unroll
    for (int mt=0;mt<4;mt++)
      #pragma unroll
      for (int nt=0;nt<4;nt++)
        acc[mt][nt] = __builtin_amdgcn_mfma_f32_16x16x32_bf16(a[mt], b[nt], acc[mt][nt], 0,0,0);
    cur ^= 1;
  }

  #pragma unroll
  for (int mt=0;mt<4;mt++){
    #pragma unroll
    for (int nt=0;nt<4;nt++){
      int col = nBase + wn + nt*16 + ln;
      int row0 = mBase + wm + mt*16 + quad*4;
      if (col < Ntrue){
        #pragma unroll
        for (int r=0;r<4;r++){
          float v = acc[mt][nt][r];
          if (MODE==2) Cb[(size_t)(row0+r)*ldc + col] = f2bf(v);
          else         Cf[(size_t)(row0+r)*ldc + col] = v;
        }
      }
    }
  }
}

// ------ out-proj GEMM 64x64, BK=128, reg-staged 2-phase, fused rms row-scale ---
// C[row,:] += rsqrt(ss[row]/DI + eps) * (A @ Bt^T); gnw already folded into Bt.
__global__ __launch_bounds__(256,2) void gemm_out(const unsigned short* __restrict__ A,
    const unsigned short* __restrict__ Bt, const float* __restrict__ ssum,
    float* __restrict__ C, int N, int K){
  __shared__ alignas(16) unsigned short As[2][64*136];
  __shared__ alignas(16) unsigned short Bs[2][64*136];
  int tid = threadIdx.x;
  int wave = tid>>6, lane = tid&63, ln = lane&15, quad = lane>>4;
  int mBase = blockIdx.y*64, nBase = blockIdx.x*64;
  int srow = tid>>2, sseg = tid&3;
  const unsigned short* Ag = A + (size_t)(mBase+srow)*K;
  const unsigned short* Bg = Bt + (size_t)(nBase+srow)*K;

  bf16x8 rA[4], rB[4];
  auto ldregs = [&](int k0){
    #pragma unroll
    for (int s=0;s<4;s++){
      rA[s] = *(const bf16x8*)(Ag + k0 + (sseg+s*4)*8);
      rB[s] = *(const bf16x8*)(Bg + k0 + (sseg+s*4)*8);
    }
  };
  auto stlds = [&](int buf){
    #pragma unroll
    for (int s=0;s<4;s++){
      *(bf16x8*)&As[buf][srow*136 + (sseg+s*4)*8] = rA[s];
      *(bf16x8*)&Bs[buf][srow*136 + (sseg+s*4)*8] = rB[s];
    }
  };

  f32x4 acc[4];
  #pragma unroll
  for (int nt=0;nt<4;nt++) acc[nt] = (f32x4){0.f,0.f,0.f,0.f};

  ldregs(0); stlds(0);
  int cur = 0;
  for (int k0=0; k0<K; k0+=128){
    __syncthreads();                 // buf[cur] writes visible
    bool pf = (k0+128 < K);
    if (pf) ldregs(k0+128);          // loads overlap MFMA below
    bf16x8 a[4];
    #pragma unroll
    for (int kq=0;kq<4;kq++)
      a[kq] = *(const bf16x8*)&As[cur][(wave*16+ln)*136 + kq*32 + quad*8];
    #pragma unroll
    for (int nt=0;nt<4;nt++){
      #pragma unroll
      for (int kq=0;kq<4;kq++){
        bf16x8 b = *(const bf16x8*)&Bs[cur][(nt*16+ln)*136 + kq*32 + quad*8];
        acc[nt] = __builtin_amdgcn_mfma_f32_16x16x32_bf16(a[kq], b, acc[nt], 0,0,0);
      }
    }
    if (pf) stlds(cur^1);            // vmcnt wait lands here, after compute
    cur ^= 1;
  }
  int row0 = mBase + wave*16 + quad*4;
  #pragma unroll
  for (int r=0;r<4;r++){
    int row = row0 + r;
    float rsv = rsqrtf(ssum[row]*(1.f/DI) + EPSF);
    #pragma unroll
    for (int nt=0;nt<4;nt++){
      int col = nBase + nt*16 + ln;
      float* p = C + (size_t)row*N + col;
      *p += acc[nt][r]*rsv;
    }
  }
}

// ---------------- depthwise causal conv (K=4) + SiLU, vectorized x8 ------------
// also zeroes ssum[0..BATCH*SEQ) for this layer's gated-rms reduction
__global__ __launch_bounds__(256) void dwconv8(const unsigned short* __restrict__ zxb,
    const float* __restrict__ w, const float* __restrict__ bias,
    unsigned short* __restrict__ out, float* __restrict__ ssum){
  int idx = blockIdx.x*256+threadIdx.x;
  if (idx < BATCH*SEQ) ssum[idx] = 0.f;
  if (idx >= BATCH*SEQ*(CDIM/8)) return;
  int c8 = idx % (CDIM/8);
  int l  = (idx/(CDIM/8)) % SEQ;
  int b  = idx / ((CDIM/8)*SEQ);
  int c = c8*8;
  float acc[8];
  #pragma unroll
  for (int j=0;j<8;j++) acc[j] = bias[c+j];
  const unsigned short* colbase = zxb + (size_t)(b*SEQ)*PDIM + DI + c;
  #pragma unroll
  for (int k=0;k<4;k++){
    int li = l-3+k;
    if (li>=0){
      bf16x8 v = *(const bf16x8*)(colbase + (size_t)li*PDIM);
      #pragma unroll
      for (int j=0;j<8;j++) acc[j] += w[(c+j)*4+k]*bf2f((unsigned short)v[j]);
    }
  }
  unsigned short o[8];
  #pragma unroll
  for (int j=0;j<8;j++) o[j] = f2bf(siluf_(acc[j]));
  *(bf16x8*)(out + (size_t)idx*8) = *(bf16x8*)&o[0];
}

// ---------------- fused prep: dt cumsum + XdT/Xdec (blocks 0..191), BT (192..255)
__global__ __launch_bounds__(256) void prep_fused(const unsigned short* __restrict__ zxb,
    const unsigned short* __restrict__ xbcb,
    const float* __restrict__ dtb, const float* __restrict__ alog,
    float* __restrict__ acs, unsigned short* __restrict__ XdT,
    unsigned short* __restrict__ Xdec, unsigned short* __restrict__ BTg){
  int blk = blockIdx.x;
  int tid = threadIdx.x;
  __shared__ alignas(16) unsigned short Xs[64*72];
  __shared__ float dts[256];
  __shared__ float dec[256];
  __shared__ float wsum[4];
  if (blk < 192){
    int c = blk % NCH, h = (blk/NCH) % NH, b = blk/(NCH*NH);
    int bh = b*NH + h;
    // phase 1: dt + chunk cumsum (wave shfl scan, 1 barrier)
    int l = c*CHUNKC + tid;
    int lane = tid & 63, wv = tid >> 6;
    float negA = -expf(alog[h]);
    float lg = bf2f(zxb[((size_t)(b*SEQ+l))*PDIM + (DI+CDIM) + h]) + dtb[h];
    float dt = softplusf_(lg);
    dts[tid] = dt;
    float s = dt*negA;
    #pragma unroll
    for (int off=1; off<64; off<<=1){
      float t = __shfl_up(s, off, 64);
      if (lane >= off) s += t;
    }
    if (lane == 63) wsum[wv] = s;
    __syncthreads();
    float pre = 0.f, tot = 0.f;
    #pragma unroll
    for (int w=0; w<4; w++){
      float wv2 = wsum[w];
      if (w < wv) pre += wv2;
      tot += wv2;
    }
    s += pre;
    acs[(size_t)bh*SEQ + l] = s;
    dec[tid] = expf(tot - s);
    // phase 2: 4 subtiles of 64 rows -> XdT, Xdec
    int srow = tid>>2, sseg = tid&3;
    int p = tid>>2, lq = tid&3;
    for (int lt2=0; lt2<4; lt2++){
      int lt = c*4 + lt2;
      __syncthreads();
      const unsigned short* src = xbcb + ((size_t)(b*SEQ) + lt*64 + srow)*CDIM + h*HD;
      #pragma unroll
      for (int s2=0;s2<2;s2++)
        *(bf16x8*)&Xs[srow*72 + (sseg+s2*4)*8] = *(const bf16x8*)(src + (sseg+s2*4)*8);
      __syncthreads();
      unsigned short o1[16], o2[16];
      #pragma unroll
      for (int li=0; li<16; li++){
        int j = lq*16+li;            // row within subtile
        int lc = lt2*64 + j;         // index within chunk
        float vv = bf2f(Xs[j*72 + p]) * dts[lc];
        o1[li] = f2bf(vv);
        o2[li] = f2bf(vv*dec[lc]);
      }
      size_t rowo = ((size_t)bh*HD + p)*SEQ + lt*64 + lq*16;
      *(bf16x8*)(XdT + rowo)     = *(bf16x8*)&o1[0];
      *(bf16x8*)(XdT + rowo + 8) = *(bf16x8*)&o1[8];
      *(bf16x8*)(Xdec + rowo)     = *(bf16x8*)&o2[0];
      *(bf16x8*)(Xdec + rowo + 8) = *(bf16x8*)&o2[8];
    }
  } else {
    int r = blk - 192;
    int nh = r & 1, lt = (r>>1) & 15, b = r >> 5;
    int srow = tid>>2, sseg = tid&3;
    const unsigned short* src = xbcb + ((size_t)(b*SEQ) + lt*64 + srow)*CDIM + DI + nh*64;
    #pragma unroll
    for (int s2=0;s2<2;s2++)
      *(bf16x8*)&Xs[srow*72 + (sseg+s2*4)*8] = *(const bf16x8*)(src + (sseg+s2*4)*8);
    __syncthreads();
    int n = tid>>2, lq = tid&3;
    unsigned short o[16];
    #pragma unroll
    for (int li=0; li<16; li++) o[li] = Xs[(lq*16+li)*72 + n];
    size_t rowo = ((size_t)b*DSTATE + nh*64 + n)*SEQ + lt*64 + lq*16;
    *(bf16x8*)(BTg + rowo)     = *(bf16x8*)&o[0];
    *(bf16x8*)(BTg + rowo + 8) = *(bf16x8*)&o[8];
  }
}

// ---------------- SSD chunk states: D[p=64][n=64] = Xdec[p][:] . BT[n][:]^T ----
__global__ __launch_bounds__(256) void ssd_states2(const unsigned short* __restrict__ Xdec,
    const unsigned short* __restrict__ BTg, float* __restrict__ states){
  int blk = blockIdx.x;
  int nh = blk & 1;
  int r = blk >> 1;
  int h = r % NH;  r /= NH;
  int c = r % NCH;
  int b = r / NCH;
  int tid = threadIdx.x, wave = tid>>6, lane = tid&63, ln = lane&15, quad = lane>>4;
  __shared__ alignas(16) unsigned short As[64*264];
  __shared__ alignas(16) unsigned short Bs[64*264];
  int bh = b*NH + h;
  {
    int srow = tid>>2, sseg = tid&3;
    const unsigned short* ga = Xdec + ((size_t)bh*HD + srow)*SEQ + c*CHUNKC;
    const unsigned short* gb = BTg + ((size_t)b*DSTATE + nh*64 + srow)*SEQ + c*CHUNKC;
    #pragma unroll
    for (int s=0;s<8;s++){
      *(bf16x8*)&As[srow*264 + (sseg+s*4)*8] = *(const bf16x8*)(ga + (sseg+s*4)*8);
      *(bf16x8*)&Bs[srow*264 + (sseg+s*4)*8] = *(const bf16x8*)(gb + (sseg+s*4)*8);
    }
  }
  __syncthreads();
  f32x4 acc[4];
  #pragma unroll
  for (int nt=0;nt<4;nt++) acc[nt] = (f32x4){0.f,0.f,0.f,0.f};
  bf16x8 a[8];
  #pragma unroll
  for (int kq=0;kq<8;kq++)
    a[kq] = *(const bf16x8*)&As[(wave*16+ln)*264 + kq*32 + quad*8];
  #pragma unroll
  for (int nt=0;nt<4;nt++){
    #pragma unroll
    for (int kq=0;kq<8;kq++){
      bf16x8 bb = *(const bf16x8*)&Bs[(nt*16+ln)*264 + kq*32 + quad*8];
      acc[nt] = __builtin_amdgcn_mfma_f32_16x16x32_bf16(a[kq], bb, acc[nt], 0,0,0);
    }
  }
  float* sp = states + (((size_t)(b*NCH+c)*NH + h) << 13) + nh*64;
  #pragma unroll
  for (int nt=0;nt<4;nt++){
    #pragma unroll
    for (int r2=0;r2<4;r2++)
      sp[(size_t)(wave*16 + quad*4 + r2)*DSTATE + nt*16 + ln] = acc[nt][r2];
  }
}

// ---------------- inter-chunk scan (prev stored bf16) ----------------
__global__ __launch_bounds__(256) void ssd_scan(const float* __restrict__ states,
    const float* __restrict__ acs, unsigned short* __restrict__ prev){
  int idx = blockIdx.x*256+threadIdx.x;
  if (idx >= BATCH*NH*HD*DSTATE) return;
  int pn = idx & 8191;
  int bh = idx >> 13;
  int h = bh % NH, b = bh / NH;
  float carry = 0.f;
  #pragma unroll
  for (int c=0;c<NCH;c++){
    size_t o = (((size_t)(b*NCH+c)*NH + h) << 13) + pn;
    prev[o] = f2bf(carry);
    float dec = expf(acs[(b*NH+h)*SEQ + c*CHUNKC + CHUNKC-1]);
    carry = carry*dec + states[o];
  }
}

// ---------------- SSD diag + off-diag + skip + gate/silu + ss reduce -----------
constexpr int CW_S  = 136;
constexpr int SB_S  = 72;
constexpr int XT_S  = 72;

__global__ __launch_bounds__(256,2) void ssd_diag2(
    const unsigned short* __restrict__ xbcb, const unsigned short* __restrict__ XdT,
    const float* __restrict__ acs, const unsigned short* __restrict__ prev,
    const float* __restrict__ dskip, const unsigned short* __restrict__ zxb,
    float* __restrict__ ssum, unsigned short* __restrict__ Y){
  int blk = blockIdx.x;
  int t = blk & 3;
  int r0 = blk >> 2;
  int h = r0 % NH;  r0 /= NH;
  int c = r0 % NCH;
  int b = r0 / NCH;

  int tid = threadIdx.x;
  int wave = tid>>6, lane = tid&63, ln = lane&15, quad = lane>>4;

  __shared__ float ac[CHUNKC];
  __shared__ alignas(16) unsigned short Cw[64*CW_S];
  __shared__ alignas(16) unsigned short Pv[64*CW_S];
  __shared__ alignas(16) unsigned short Bt[64*CW_S];
  __shared__ alignas(16) unsigned short Xt[64*XT_S];
  __shared__ alignas(16) unsigned short Sb[4][16*SB_S];

  const int bh = b*NH + h;
  const size_t rowbase = (size_t)(b*SEQ + c*CHUNKC);

  ac[tid] = acs[(size_t)bh*SEQ + c*CHUNKC + tid];

  {
    int srow = tid>>2, sseg = tid&3;
    const unsigned short* gc = xbcb + (rowbase + t*64 + srow)*CDIM + DI + DSTATE;
    const unsigned short* gp = prev + (((size_t)(b*NCH+c)*NH + h) << 13) + (size_t)srow*DSTATE;
    #pragma unroll
    for (int s=0;s<4;s++){
      *(bf16x8*)&Cw[srow*CW_S + (sseg+s*4)*8] = *(const bf16x8*)(gc + (sseg+s*4)*8);
      *(bf16x8*)&Pv[srow*CW_S + (sseg+s*4)*8] = *(const bf16x8*)(gp + (sseg+s*4)*8);
    }
  }
  __syncthreads();

  bf16x8 aC[4];
  #pragma unroll
  for (int kq=0;kq<4;kq++)
    aC[kq] = *(const bf16x8*)&Cw[(wave*16+ln)*CW_S + kq*32 + quad*8];

  f32x4 yacc[4];
  #pragma unroll
  for (int ps=0;ps<4;ps++) yacc[ps] = (f32x4){0.f,0.f,0.f,0.f};

  for (int jt=0; jt<=t; jt++){
    __syncthreads();
    {
      int srow = tid>>2, sseg = tid&3;
      const unsigned short* gbm = xbcb + (rowbase + jt*64 + srow)*CDIM + DI;
      #pragma unroll
      for (int s=0;s<4;s++)
        *(bf16x8*)&Bt[srow*CW_S + (sseg+s*4)*8] = *(const bf16x8*)(gbm + (sseg+s*4)*8);
      const unsigned short* gx = XdT + ((size_t)bh*HD + srow)*SEQ + c*CHUNKC + jt*64;
      #pragma unroll
      for (int s=0;s<2;s++)
        *(bf16x8*)&Xt[srow*XT_S + (sseg+s*4)*8] = *(const bf16x8*)(gx + (sseg+s*4)*8);
    }
    __syncthreads();

    #pragma unroll
    for (int js=0; js<4; js++){
      f32x4 s = (f32x4){0.f,0.f,0.f,0.f};
      #pragma unroll
      for (int kq=0;kq<4;kq++){
        bf16x8 bB = *(const bf16x8*)&Bt[(js*16+ln)*CW_S + kq*32 + quad*8];
        s = __builtin_amdgcn_mfma_f32_16x16x32_bf16(aC[kq], bB, s, 0,0,0);
      }
      int jc = jt*64 + js*16 + ln;
      #pragma unroll
      for (int r=0;r<4;r++){
        int icl = t*64 + wave*16 + quad*4 + r;
        float d = (jc<=icl) ? (ac[icl]-ac[jc]) : -1e30f;
        Sb[wave][(quad*4+r)*SB_S + js*16 + ln] = f2bf(expf(d)*s[r]);
      }
    }
    bf16x8 aS[2];
    #pragma unroll
    for (int kq=0;kq<2;kq++)
      aS[kq] = *(const bf16x8*)&Sb[wave][ln*SB_S + kq*32 + quad*8];
    #pragma unroll
    for (int ps=0;ps<4;ps++){
      #pragma unroll
      for (int kq=0;kq<2;kq++){
        bf16x8 bX = *(const bf16x8*)&Xt[(ps*16+ln)*XT_S + kq*32 + quad*8];
        yacc[ps] = __builtin_amdgcn_mfma_f32_16x16x32_bf16(aS[kq], bX, yacc[ps], 0,0,0);
      }
    }
  }

  f32x4 oacc[4];
  #pragma unroll
  for (int ps=0;ps<4;ps++) oacc[ps] = (f32x4){0.f,0.f,0.f,0.f};
  #pragma unroll
  for (int ps=0;ps<4;ps++){
    #pragma unroll
    for (int kq=0;kq<4;kq++){
      bf16x8 bP = *(const bf16x8*)&Pv[(ps*16+ln)*CW_S + kq*32 + quad*8];
      oacc[ps] = __builtin_amdgcn_mfma_f32_16x16x32_bf16(aC[kq], bP, oacc[ps], 0,0,0);
    }
  }

  float dsk = dskip[h];
  #pragma unroll
  for (int r=0;r<4;r++){
    int icl = t*64 + wave*16 + quad*4 + r;
    float ei = expf(ac[icl]);
    size_t l = rowbase + icl;
    float rss = 0.f;
    #pragma unroll
    for (int ps=0;ps<4;ps++){
      int p = ps*16 + ln;
      float xraw = bf2f(xbcb[l*CDIM + h*HD + p]);
      float zv = bf2f(zxb[l*PDIM + h*HD + p]);
      float yg = (yacc[ps][r] + ei*oacc[ps][r] + dsk*xraw) * siluf_(zv);
      Y[l*DI + h*HD + p] = f2bf(yg);
      rss += yg*yg;
    }
    // reduce over the 16 lanes of this quad (aligned 16-lane group)
    rss += __shfl_down(rss, 8, 64);
    rss += __shfl_down(rss, 4, 64);
    rss += __shfl_down(rss, 2, 64);
    rss += __shfl_down(rss, 1, 64);
    if (ln == 0) atomicAdd(&ssum[l], rss);
  }
}

// ---------------- final pooling + head -----------------------------------------
__global__ __launch_bounds__(256) void mean_pool(const float* __restrict__ hn,
    float* __restrict__ pooled){
  int idx = blockIdx.x*256+threadIdx.x;
  if (idx >= BATCH*DM) return;
  int b = idx / DM, d = idx % DM;
  float s = 0.f;
  for (int l=0;l<SEQ;l++) s += hn[((size_t)(b*SEQ+l))*DM + d];
  pooled[idx] = s * (1.f/SEQ);
}

__global__ __launch_bounds__(512) void head_k(const float* __restrict__ pooled,
    const float* __restrict__ w1, const float* __restrict__ b1,
    const float* __restrict__ g, const float* __restrict__ bb,
    const float* __restrict__ mn, const float* __restrict__ vr,
    const float* __restrict__ w2, const float* __restrict__ b2,
    float* __restrict__ out){
  int b = blockIdx.x;
  int j = threadIdx.x;
  __shared__ float f[512];
  __shared__ float pl[DM];
  for (int t=j; t<DM; t+=512) pl[t] = pooled[b*DM+t];
  __syncthreads();
  float s = b1[j];
  for (int k=0;k<DM;k++) s += pl[k]*w1[k*512+j];
  s = (s-mn[j])*(g[j]*rsqrtf(vr[j]+EPSF)) + bb[j];
  f[j] = fmaxf(s,0.f);
  __syncthreads();
  if (j < 27){
    float o = b2[j];
    for (int k=0;k<512;k++) o += f[k]*w2[k*27+j];
    out[b*27+j] = o;
  }
}

extern "C" void kernel_launch(void* const* d_in, const int* in_sizes, int n_in,
                              void* d_out, int out_size, void* d_ws, size_t ws_size,
                              hipStream_t stream){
  const float* x      = (const float*)d_in[0];
  const float* c1_w   = (const float*)d_in[1];
  const float* c1_b   = (const float*)d_in[2];
  const float* bn1_g  = (const float*)d_in[3];
  const float* bn1_b  = (const float*)d_in[4];
  const float* bn1_m  = (const float*)d_in[5];
  const float* bn1_v  = (const float*)d_in[6];
  const float* c2_w   = (const float*)d_in[7];
  const float* c2_b   = (const float*)d_in[8];
  const float* bn2_g  = (const float*)d_in[9];
  const float* bn2_b  = (const float*)d_in[10];
  const float* bn2_m  = (const float*)d_in[11];
  const float* bn2_v  = (const float*)d_in[12];
  const float* c3_w   = (const float*)d_in[13];
  const float* c3_b   = (const float*)d_in[14];
  const float* bn3_g  = (const float*)d_in[15];
  const float* bn3_b  = (const float*)d_in[16];
  const float* bn3_m  = (const float*)d_in[17];
  const float* bn3_v  = (const float*)d_in[18];
  const float* ln_w   = (const float*)d_in[19];
  const float* inpw   = (const float*)d_in[20];
  const float* convw  = (const float*)d_in[21];
  const float* convb  = (const float*)d_in[22];
  const float* dtb    = (const float*)d_in[23];
  const float* alog   = (const float*)d_in[24];
  const float* dskip  = (const float*)d_in[25];
  const float* gnw    = (const float*)d_in[26];
  const float* outw   = (const float*)d_in[27];
  const float* normfw = (const float*)d_in[28];
  const float* fc1w   = (const float*)d_in[29];
  const float* fc1b   = (const float*)d_in[30];
  const float* bncg   = (const float*)d_in[31];
  const float* bncb   = (const float*)d_in[32];
  const float* bncm   = (const float*)d_in[33];
  const float* bncv   = (const float*)d_in[34];
  const float* fc2w   = (const float*)d_in[35];
  const float* fc2b   = (const float*)d_in[36];
  (void)in_sizes; (void)n_in; (void)out_size;

  char* ws = (char*)d_ws;
  size_t off = 0;
  auto alloc = [&](size_t bytes){
    char* p = ws + off;
    off += (bytes + 255) & ~(size_t)255;
    return (void*)p;
  };
  float* h1  = (float*)alloc((size_t)BATCH*192*LS1*4);
  float* h   = (float*)alloc((size_t)BATCH*SEQ*DM*4);
  float* hn  = (float*)alloc((size_t)BATCH*SEQ*DM*4);
  unsigned short* zxb = (unsigned short*)alloc((size_t)BATCH*SEQ*PDIM*2);
  unsigned short* xbcb= (unsigned short*)alloc((size_t)BATCH*SEQ*CDIM*2);
  float* acs = (float*)alloc((size_t)BATCH*NH*SEQ*4);
  float* st  = (float*)alloc((size_t)BATCH*NCH*NH*HD*DSTATE*4);
  unsigned short* pv  = (unsigned short*)alloc((size_t)BATCH*NCH*NH*HD*DSTATE*2);
  unsigned short* Y   = (unsigned short*)alloc((size_t)BATCH*SEQ*DI*2);
  float* pooled = (float*)alloc((size_t)BATCH*DM*4);
  unsigned short* hnb   = (unsigned short*)alloc((size_t)BATCH*SEQ*DM*2);
  float* ssum = (float*)alloc((size_t)BATCH*SEQ*4);
  unsigned short* XdTg  = (unsigned short*)alloc((size_t)BATCH*NH*HD*SEQ*2);
  unsigned short* Xdecg = (unsigned short*)alloc((size_t)BATCH*NH*HD*SEQ*2);
  unsigned short* BTg   = (unsigned short*)alloc((size_t)BATCH*DSTATE*SEQ*2);
  unsigned short* xT2   = (unsigned short*)alloc((size_t)BATCH*XT2_BSTRIDE*2);
  unsigned short* xT3   = (unsigned short*)alloc((size_t)BATCH*XT3_BSTRIDE*2);
  unsigned short* wt2   = (unsigned short*)alloc((size_t)384*576*2);
  unsigned short* wt3   = (unsigned short*)alloc((size_t)768*1152*2);

  // weight buffers: all-layer (hoisted) if ws allows, else per-layer fallback
  const size_t wtin_l  = (size_t)PPAD*DM;     // elems per layer
  const size_t wtout_l = (size_t)DM*DI;
  size_t base_off = off;
  size_t big_bytes = (wtin_l + wtout_l)*NLAYER*2 + 512;
  bool big = (ws_size >= base_off + big_bytes);
  unsigned short *wtinA, *wtoutA;
  if (big){
    wtinA  = (unsigned short*)alloc(wtin_l*NLAYER*2);
    wtoutA = (unsigned short*)alloc(wtout_l*NLAYER*2);
  } else {
    wtinA  = (unsigned short*)alloc(wtin_l*2);
    wtoutA = (unsigned short*)alloc(wtout_l*2);
  }

  // ---- one-time weight prep ----
  wt_reorder<<<(384*192*3+255)/256,256,0,stream>>>(c2_w, wt2, 384, 192, 3);
  wt_reorder<<<(768*384*3+255)/256,256,0,stream>>>(c3_w, wt3, 768, 384, 3);
  zero_rows3<<<(2*2*384+255)/256,256,0,stream>>>(xT3);
  if (big){
    transpose_cvt_l<<<dim3(PPAD/32, DM/32, NLAYER),256,0,stream>>>(
        inpw, wtinA, DM, PDIM, PPAD, (size_t)DM*PDIM, wtin_l, nullptr, 0);
    // fold gnw into out_proj weight (rms column weight is the GEMM K dim)
    transpose_cvt_l<<<dim3(DM/32, DI/32, NLAYER),256,0,stream>>>(
        outw, wtoutA, DI, DM, DM, (size_t)DI*DM, wtout_l, gnw, (size_t)DI);
  }

  // ---- stem ----
  conv_stem1<<<(BATCH*192*LS1+255)/256,256,0,stream>>>(x, c1_w,c1_b, bn1_g,bn1_b,bn1_m,bn1_v, h1);
  transpose_pad_bf<<<dim3(LS1/32, 192/32, BATCH),256,0,stream>>>(
      h1, xT2, 192, LS1, (size_t)192*LS1, XT2_BSTRIDE);
  gemm_stem<0><<<dim3(384/128, 16),256,0,stream>>>(
      xT2, wt2, c2_b, bn2_g, bn2_b, bn2_m, bn2_v, xT3, nullptr,
      576, 384, XT2_BSTRIDE);
  gemm_stem<1><<<dim3(768/128, 16),256,0,stream>>>(
      xT3, wt3, c3_b, bn3_g, bn3_b, bn3_m, bn3_v, nullptr, h,
      1152, 384, XT3_BSTRIDE);

  const int M = BATCH*SEQ;  // 2048
  for (int l=0; l<NLAYER; l++){
    unsigned short* wtin  = big ? (wtinA  + (size_t)l*wtin_l)  : wtinA;
    unsigned short* wtout = big ? (wtoutA + (size_t)l*wtout_l) : wtoutA;
    if (!big){
      transpose_cvt_l<<<dim3(PPAD/32, DM/32, 1),256,0,stream>>>(
          inpw + (size_t)l*DM*PDIM, wtin, DM, PDIM, PPAD, 0, 0, nullptr, 0);
      transpose_cvt_l<<<dim3(DM/32, DI/32, 1),256,0,stream>>>(
          outw + (size_t)l*DI*DM, wtout, DI, DM, DM, 0, 0, gnw + (size_t)l*DI, 0);
    }

    rmsnorm768<1><<<M,256,0,stream>>>(h, ln_w + (size_t)l*DM, nullptr, hnb);
    gemm_bf16<2><<<dim3(PPAD/128, M/128),256,0,stream>>>(hnb, wtin, nullptr, zxb, PDIM, DM, PDIM);
    dwconv8<<<(BATCH*SEQ*(CDIM/8)+255)/256,256,0,stream>>>(zxb, convw + (size_t)l*CDIM*4, convb + (size_t)l*CDIM, xbcb, ssum);
    prep_fused<<<256,256,0,stream>>>(zxb, xbcb, dtb + l*NH, alog + l*NH, acs, XdTg, Xdecg, BTg);
    ssd_states2<<<BATCH*NCH*NH*2,256,0,stream>>>(Xdecg, BTg, st);
    ssd_scan<<<(BATCH*NH*HD*DSTATE+255)/256,256,0,stream>>>(st, acs, pv);
    ssd_diag2<<<BATCH*NCH*NH*4,256,0,stream>>>(xbcb, XdTg, acs, pv, dskip + l*NH, zxb, ssum, Y);
    gemm_out<<<dim3(DM/64, M/64),256,0,stream>>>(Y, wtout, ssum, h, DM, DI);
  }

  rmsnorm768<0><<<M,256,0,stream>>>(h, normfw, hn, nullptr);
  mean_pool<<<(BATCH*DM+255)/256,256,0,stream>>>(hn, pooled);
  head_k<<<BATCH,512,0,stream>>>(pooled, fc1w, fc1b, bncg,bncb,bncm,bncv, fc2w, fc2b, (float*)d_out);
}

// Round 3
// 3354.363 us; speedup vs baseline: 1.3149x; 1.1194x over previous
//
#include <hip/hip_runtime.h>
#include <math.h>

#define DEV __device__ __forceinline__

constexpr int BATCH = 2;
constexpr int L0 = 4096;
constexpr int LS1 = 2048;
constexpr int LS2 = 1024;
constexpr int SEQ = 1024;
constexpr int DM = 768;
constexpr int NH = 24;
constexpr int HD = 64;
constexpr int DI = 1536;
constexpr int DSTATE = 128;
constexpr int CDIM = 1792;   // DI + 2*DSTATE
constexpr int PDIM = 3352;   // 2*DI + 2*DSTATE + NH
constexpr int PPAD = 3456;   // PDIM padded to 27*128
constexpr int CHUNKC = 256;
constexpr int NCH = 4;
constexpr int NLAYER = 24;
constexpr float EPSF = 1e-5f;

// padded transposed stem buffers
constexpr int XT2_ROWS = 2050;             // l=-1..2048 (row = l+1)
constexpr size_t XT2_BSTRIDE = (size_t)XT2_ROWS*192;
constexpr int XT3_ROWS = 1026;             // l=-1..1024 (row = l+1)
constexpr size_t XT3_BSTRIDE = (size_t)XT3_ROWS*384;

typedef short bf16x8 __attribute__((ext_vector_type(8)));
typedef float f32x4 __attribute__((ext_vector_type(4)));

DEV float sigmoidf_(float x){ return 1.f/(1.f+expf(-x)); }
DEV float siluf_(float x){ return x*sigmoidf_(x); }
DEV float geluf_(float x){ return 0.5f*x*(1.f+erff(x*0.70710678118654752440f)); }
DEV float softplusf_(float x){ return fmaxf(x,0.f) + log1pf(expf(-fabsf(x))); }

DEV unsigned short f2bf(float x){
  union { float f; unsigned int u; } v; v.f = x;
  unsigned int u = v.u;
  unsigned int r = (u + 0x7fffu + ((u>>16)&1u)) >> 16;
  return (unsigned short)r;
}
DEV float bf2f(unsigned short u){
  union { unsigned int u; float f; } v; v.u = ((unsigned int)u)<<16; return v.f;
}

DEV void load_lds16(const void* g, void* l){
  __builtin_amdgcn_global_load_lds(
      (const __attribute__((address_space(1))) unsigned int*)g,
      (__attribute__((address_space(3))) unsigned int*)l,
      16, 0, 0);
}

DEV float block_sum_256(float v, float* red4){
  #pragma unroll
  for (int o=32;o>0;o>>=1) v += __shfl_down(v,o,64);
  int tid = threadIdx.x;
  __syncthreads();
  if ((tid&63)==0) red4[tid>>6]=v;
  __syncthreads();
  return red4[0]+red4[1]+red4[2]+red4[3];
}

// ---------------- stem1 (fp32, small K) ----------------
__global__ __launch_bounds__(256) void conv_stem1(const float* __restrict__ x,
    const float* __restrict__ w, const float* __restrict__ bias,
    const float* __restrict__ g, const float* __restrict__ bb,
    const float* __restrict__ mn, const float* __restrict__ vr,
    float* __restrict__ out){
  int idx = blockIdx.x*256+threadIdx.x;
  if (idx >= BATCH*192*LS1) return;
  int lo = idx & (LS1-1);
  int co = (idx >> 11) % 192;
  int b  = idx / (192*LS1);
  float s = bias[co];
  const float* wr = w + co*60;
  #pragma unroll
  for (int ci=0; ci<12; ci++){
    const float* xr = x + ((size_t)(b*12+ci))*L0;
    #pragma unroll
    for (int k=0;k<5;k++){
      int li = lo*2 + k - 2;
      if (li>=0 && li<L0) s += wr[ci*5+k]*xr[li];
    }
  }
  s = geluf_(s);
  s = (s-mn[co])*(g[co]*rsqrtf(vr[co]+EPSF)) + bb[co];
  out[idx] = s;
}

// ---- stem weight reorder: w[co][ci][k] fp32 -> wt[co][k*CI+ci] bf16 ----
__global__ __launch_bounds__(256) void wt_reorder(const float* __restrict__ w,
    unsigned short* __restrict__ o, int CO, int CI, int KK){
  int idx = blockIdx.x*256+threadIdx.x;
  if (idx >= CO*CI*KK) return;
  int ci = idx % CI;
  int k  = (idx/CI) % KK;
  int co = idx/(CI*KK);
  o[idx] = f2bf(w[(size_t)co*CI*KK + (size_t)ci*KK + k]);
}

// ---- transpose fp32 [R][C] (per batch) -> bf16 padded [C+2][R], row=c+1 ----
__global__ __launch_bounds__(256) void transpose_pad_bf(const float* __restrict__ in,
    unsigned short* __restrict__ out, int R, int C,
    size_t in_bstride, size_t out_bstride){
  const float* ib = in + (size_t)blockIdx.z*in_bstride;
  unsigned short* ob = out + (size_t)blockIdx.z*out_bstride;
  __shared__ float t[32][33];
  int c0 = blockIdx.x*32, r0 = blockIdx.y*32;
  int tx = threadIdx.x & 31, ty = threadIdx.x >> 5;
  #pragma unroll
  for (int i=0;i<32;i+=8)
    t[ty+i][tx] = ib[(size_t)(r0+ty+i)*C + c0+tx];
  __syncthreads();
  #pragma unroll
  for (int i=0;i<32;i+=8)
    ob[(size_t)(c0+ty+i+1)*R + r0+tx] = f2bf(t[tx][ty+i]);
  if (blockIdx.x==0 && ty==0){
    ob[r0+tx] = 0;
    ob[(size_t)(C+1)*R + r0+tx] = 0;
  }
}

// ---- zero pad rows of xT3 (rows 0 and 1025, both batches) ----
__global__ __launch_bounds__(256) void zero_rows3(unsigned short* __restrict__ xT3){
  int i = blockIdx.x*256+threadIdx.x;
  if (i >= 2*2*384) return;
  int ci = i % 384;
  int r  = (i/384) & 1;
  int b2 = i / 768;
  xT3[(size_t)b2*XT3_BSTRIDE + (size_t)(r?1025:0)*384 + ci] = 0;
}

// ---- implicit-GEMM stem conv, BK=64: A = overlapping windows of padded xT ----
// MODE 0: stem2 -> bf16 into padded xT3 (row lo+1); MODE 1: stem3 -> fp32 h
template<int MODE>
__global__ __launch_bounds__(256,2) void gemm_stem(const unsigned short* __restrict__ A,
    const unsigned short* __restrict__ Bt,
    const float* __restrict__ bias, const float* __restrict__ g,
    const float* __restrict__ bbn, const float* __restrict__ mn,
    const float* __restrict__ vr,
    unsigned short* __restrict__ Ob, float* __restrict__ Of,
    int K, int rowStride, size_t batchStride){
  __shared__ alignas(16) unsigned short As[2][128*64];
  __shared__ alignas(16) unsigned short Bs[2][128*64];
  int tid = threadIdx.x;
  int wave = tid >> 6, lane = tid & 63;
  int mBase = blockIdx.y*128, nBase = blockIdx.x*128;
  int bidx = mBase >> 10;            // rows per batch = 1024
  int mloc = mBase & 1023;
  const unsigned short* Ab = A + (size_t)bidx*batchStride + (size_t)mloc*rowStride;
  const size_t rs2 = (size_t)rowStride*2;
  const size_t K2 = (size_t)K*2;
  const char* Ag[4]; const char* Bg[4];
  #pragma unroll
  for (int c2=0;c2<4;c2++){
    int o = c2*4096 + wave*1024 + lane*16;
    Ag[c2] = (const char*)Ab + (size_t)(o>>7)*rs2 + (o&127);
    Bg[c2] = (const char*)Bt + (size_t)(nBase + (o>>7))*K2 + (o&127);
  }

  int wm = (wave>>1)*64, wn = (wave&1)*64;
  int ln = lane & 15, quad = lane >> 4;

  f32x4 acc[4][4];
  #pragma unroll
  for (int i=0;i<4;i++)
    #pragma unroll
    for (int j=0;j<4;j++) acc[i][j] = (f32x4){0.f,0.f,0.f,0.f};

  auto stage = [&](int buf, int k0){
    size_t kb = (size_t)k0*2;
    #pragma unroll
    for (int c2=0;c2<4;c2++){
      load_lds16(Ag[c2] + kb, (char*)(&As[buf][0]) + c2*4096 + wave*1024);
      load_lds16(Bg[c2] + kb, (char*)(&Bs[buf][0]) + c2*4096 + wave*1024);
    }
  };

  stage(0, 0);
  int cur = 0;
  for (int k0=0; k0<K; k0+=64){
    __syncthreads();
    if (k0+64 < K) stage(cur^1, k0+64);
    bf16x8 a[2][4], b[2][4];
    #pragma unroll
    for (int kh=0;kh<2;kh++){
      #pragma unroll
      for (int mt=0;mt<4;mt++)
        a[kh][mt] = *(const bf16x8*)((const char*)(&As[cur][0]) + (size_t)(wm+mt*16+ln)*128 + kh*64 + quad*16);
      #pragma unroll
      for (int nt=0;nt<4;nt++)
        b[kh][nt] = *(const bf16x8*)((const char*)(&Bs[cur][0]) + (size_t)(wn+nt*16+ln)*128 + kh*64 + quad*16);
    }
    #pragma unroll
    for (int kh=0;kh<2;kh++)
      #pragma unroll
      for (int mt=0;mt<4;mt++)
        #pragma unroll
        for (int nt=0;nt<4;nt++)
          acc[mt][nt] = __builtin_amdgcn_mfma_f32_16x16x32_bf16(a[kh][mt], b[kh][nt], acc[mt][nt], 0,0,0);
    cur ^= 1;
  }

  #pragma unroll
  for (int nt=0;nt<4;nt++){
    int col = nBase + wn + nt*16 + ln;
    float bs = bias[col];
    float sc = g[col]*rsqrtf(vr[col]+EPSF);
    float bnm2 = mn[col], bnb2 = bbn[col];
    #pragma unroll
    for (int mt=0;mt<4;mt++){
      int row0 = mBase + wm + mt*16 + quad*4;
      #pragma unroll
      for (int r=0;r<4;r++){
        int row = row0 + r;
        float v = acc[mt][nt][r] + bs;
        v = geluf_(v);
        v = (v-bnm2)*sc + bnb2;
        if (MODE==0){
          int b2 = row >> 10, lr = row & 1023;
          Ob[(size_t)b2*XT3_BSTRIDE + (size_t)(lr+1)*384 + col] = f2bf(v);
        } else {
          Of[(size_t)row*DM + col] = v;
        }
      }
    }
  }
}

// ---------------- rmsnorm (D=768) ----------------
template<int BF>
__global__ __launch_bounds__(256) void rmsnorm768(const float* __restrict__ in,
    const float* __restrict__ w, float* __restrict__ outf, unsigned short* __restrict__ outb){
  int row = blockIdx.x;
  const float* p = in + (size_t)row*DM;
  float v0[3]; float ss=0.f;
  #pragma unroll
  for (int t=0;t<3;t++){ float q = p[threadIdx.x + t*256]; v0[t]=q; ss+=q*q; }
  __shared__ float red[4];
  float tot = block_sum_256(ss, red);
  float sc = rsqrtf(tot*(1.f/DM) + EPSF);
  #pragma unroll
  for (int t=0;t<3;t++){
    int d = threadIdx.x + t*256;
    float o = v0[t]*sc*w[d];
    if (BF) outb[(size_t)row*DM + d] = f2bf(o);
    else    outf[(size_t)row*DM + d] = o;
  }
}

// ------- transpose + fp32->bf16, batched over layers via blockIdx.z ------------
// rsc: optional per-input-row scale (used to fold gnw into out_proj weight)
__global__ __launch_bounds__(256) void transpose_cvt_l(const float* __restrict__ in0,
    unsigned short* __restrict__ out0, int R, int Cin, int Cpad,
    size_t in_lstride, size_t out_lstride,
    const float* __restrict__ rsc, size_t rsc_stride){
  const float* in = in0 + (size_t)blockIdx.z*in_lstride;
  unsigned short* out = out0 + (size_t)blockIdx.z*out_lstride;
  const float* rs = rsc ? (rsc + (size_t)blockIdx.z*rsc_stride) : nullptr;
  __shared__ float t[32][33];
  int c0 = blockIdx.x*32, r0 = blockIdx.y*32;
  int tx = threadIdx.x & 31, ty = threadIdx.x >> 5;
  #pragma unroll
  for (int i=0;i<32;i+=8){
    int r = r0+ty+i, c = c0+tx;
    float v = (c<Cin) ? in[(size_t)r*Cin + c] : 0.f;
    if (rs) v *= rs[r];
    t[ty+i][tx] = v;
  }
  __syncthreads();
  #pragma unroll
  for (int i=0;i<32;i+=8){
    int c = c0+ty+i, r = r0+tx;
    if (c < Cpad) out[(size_t)c*R + r] = f2bf(t[tx][ty+i]);
  }
}

// ---------------- bf16 MFMA GEMM 128x128, BK=64, 2-phase dbuf prefetch ---------
template<int MODE>
__global__ __launch_bounds__(256,2) void gemm_bf16(const unsigned short* __restrict__ A,
    const unsigned short* __restrict__ Bt, float* __restrict__ Cf,
    unsigned short* __restrict__ Cb, int Ntrue, int K, int ldc){
  __shared__ alignas(16) unsigned short As[2][128*64];
  __shared__ alignas(16) unsigned short Bs[2][128*64];
  int tid = threadIdx.x;
  int wave = tid >> 6, lane = tid & 63;
  int mBase = blockIdx.y*128, nBase = blockIdx.x*128;
  const size_t K2 = (size_t)K*2;
  const char* Ag[4]; const char* Bg[4];
  #pragma unroll
  for (int c2=0;c2<4;c2++){
    int o = c2*4096 + wave*1024 + lane*16;
    Ag[c2] = (const char*)A + (size_t)(mBase + (o>>7))*K2 + (o&127);
    Bg[c2] = (const char*)Bt + (size_t)(nBase + (o>>7))*K2 + (o&127);
  }

  int wm = (wave>>1)*64, wn = (wave&1)*64;
  int ln = lane & 15, quad = lane >> 4;

  f32x4 acc[4][4];
  #pragma unroll
  for (int i=0;i<4;i++)
    #pragma unroll
    for (int j=0;j<4;j++) acc[i][j] = (f32x4){0.f,0.f,0.f,0.f};

  auto stage = [&](int buf, int k0){
    size_t kb = (size_t)k0*2;
    #pragma unroll
    for (int c2=0;c2<4;c2++){
      load_lds16(Ag[c2] + kb, (char*)(&As[buf][0]) + c2*4096 + wave*1024);
      load_lds16(Bg[c2] + kb, (char*)(&Bs[buf][0]) + c2*4096 + wave*1024);
    }
  };

  stage(0, 0);
  int cur = 0;
  for (int k0=0; k0<K; k0+=64){
    __syncthreads();                 // drains vmcnt: buf[cur] ready
    if (k0+64 < K) stage(cur^1, k0+64);  // prefetch overlaps MFMA below
    bf16x8 a[2][4], b[2][4];
    #pragma unroll
    for (int kh=0;kh<2;kh++){
      #pragma unroll
      for (int mt=0;mt<4;mt++)
        a[kh][mt] = *(const bf16x8*)((const char*)(&As[cur][0]) + (size_t)(wm+mt*16+ln)*128 + kh*64 + quad*16);
      #pragma unroll
      for (int nt=0;nt<4;nt++)
        b[kh][nt] = *(const bf16x8*)((const char*)(&Bs[cur][0]) + (size_t)(wn+nt*16+ln)*128 + kh*64 + quad*16);
    }
    #pragma unroll
    for (int kh=0;kh<2;kh++)
      #pragma unroll
      for (int mt=0;mt<4;mt++)
        #pragma unroll
        for (int nt=0;nt<4;nt++)
          acc[mt][nt] = __builtin_amdgcn_mfma_f32_16x16x32_bf16(a[kh][mt], b[kh][nt], acc[mt][nt], 0,0,0);
    cur ^= 1;
  }

  #pragma unroll
  for (int mt=0;mt<4;mt++){
    #pragma unroll
    for (int nt=0;nt<4;nt++){
      int col = nBase + wn + nt*16 + ln;
      int row0 = mBase + wm + mt*16 + quad*4;
      if (col < Ntrue){
        #pragma unroll
        for (int r=0;r<4;r++){
          float v = acc[mt][nt][r];
          if (MODE==2) Cb[(size_t)(row0+r)*ldc + col] = f2bf(v);
          else         Cf[(size_t)(row0+r)*ldc + col] = v;
        }
      }
    }
  }
}

// ------ out-proj GEMM 64x64, BK=128, reg-staged 2-phase, fused rms row-scale ---
// C[row,:] += rsqrt(ss[row]/DI + eps) * (A @ Bt^T); gnw already folded into Bt.
__global__ __launch_bounds__(256,2) void gemm_out(const unsigned short* __restrict__ A,
    const unsigned short* __restrict__ Bt, const float* __restrict__ ssum,
    float* __restrict__ C, int N, int K){
  __shared__ alignas(16) unsigned short As[2][64*136];
  __shared__ alignas(16) unsigned short Bs[2][64*136];
  int tid = threadIdx.x;
  int wave = tid>>6, lane = tid&63, ln = lane&15, quad = lane>>4;
  int mBase = blockIdx.y*64, nBase = blockIdx.x*64;
  int srow = tid>>2, sseg = tid&3;
  const unsigned short* Ag = A + (size_t)(mBase+srow)*K;
  const unsigned short* Bg = Bt + (size_t)(nBase+srow)*K;

  bf16x8 rA[4], rB[4];
  auto ldregs = [&](int k0){
    #pragma unroll
    for (int s=0;s<4;s++){
      rA[s] = *(const bf16x8*)(Ag + k0 + (sseg+s*4)*8);
      rB[s] = *(const bf16x8*)(Bg + k0 + (sseg+s*4)*8);
    }
  };
  auto stlds = [&](int buf){
    #pragma unroll
    for (int s=0;s<4;s++){
      *(bf16x8*)&As[buf][srow*136 + (sseg+s*4)*8] = rA[s];
      *(bf16x8*)&Bs[buf][srow*136 + (sseg+s*4)*8] = rB[s];
    }
  };

  f32x4 acc[4];
  #pragma unroll
  for (int nt=0;nt<4;nt++) acc[nt] = (f32x4){0.f,0.f,0.f,0.f};

  ldregs(0); stlds(0);
  int cur = 0;
  for (int k0=0; k0<K; k0+=128){
    __syncthreads();                 // buf[cur] writes visible
    bool pf = (k0+128 < K);
    if (pf) ldregs(k0+128);          // loads overlap MFMA below
    bf16x8 a[4];
    #pragma unroll
    for (int kq=0;kq<4;kq++)
      a[kq] = *(const bf16x8*)&As[cur][(wave*16+ln)*136 + kq*32 + quad*8];
    #pragma unroll
    for (int nt=0;nt<4;nt++){
      #pragma unroll
      for (int kq=0;kq<4;kq++){
        bf16x8 b = *(const bf16x8*)&Bs[cur][(nt*16+ln)*136 + kq*32 + quad*8];
        acc[nt] = __builtin_amdgcn_mfma_f32_16x16x32_bf16(a[kq], b, acc[nt], 0,0,0);
      }
    }
    if (pf) stlds(cur^1);            // vmcnt wait lands here, after compute
    cur ^= 1;
  }
  int row0 = mBase + wave*16 + quad*4;
  #pragma unroll
  for (int r=0;r<4;r++){
    int row = row0 + r;
    float rsv = rsqrtf(ssum[row]*(1.f/DI) + EPSF);
    #pragma unroll
    for (int nt=0;nt<4;nt++){
      int col = nBase + nt*16 + ln;
      float* p = C + (size_t)row*N + col;
      *p += acc[nt][r]*rsv;
    }
  }
}

// -------- fused prep: inline dwconv+SiLU from zxb, dt cumsum, XdT/Xdec,
//          xbcb writes (X,B,C sections), BT transpose. Grid = 320 blocks.
//          blocks 0..191: (b,c,h) main (X section); 192..319: B/C sections.
__global__ __launch_bounds__(256) void prep_fused(const unsigned short* __restrict__ zxb,
    unsigned short* __restrict__ xbcb,
    const float* __restrict__ cw, const float* __restrict__ cb,
    const float* __restrict__ dtb, const float* __restrict__ alog,
    float* __restrict__ acs, unsigned short* __restrict__ XdT,
    unsigned short* __restrict__ Xdec, unsigned short* __restrict__ BTg,
    float* __restrict__ ssum){
  int blk = blockIdx.x;
  int tid = threadIdx.x;
  __shared__ alignas(16) unsigned short Xs[64*72];
  __shared__ float dts[256];
  __shared__ float dec[256];
  __shared__ float wsum[4];
  __shared__ float wsh[256];   // 64 cols x 4 taps
  __shared__ float bsh[64];
  if (blk < 192){
    int c = blk % NCH, h = (blk/NCH) % NH, b = blk/(NCH*NH);
    int bh = b*NH + h;
    int cb0 = h*64;                       // xbcb col base (X section)
    // conv weight preload for these 64 cols
    wsh[tid] = cw[(cb0 + (tid>>2))*4 + (tid&3)];
    if (tid < 64) bsh[tid] = cb[cb0 + tid];
    if (h == 0) ssum[(size_t)b*SEQ + c*CHUNKC + tid] = 0.f;
    // phase 1: dt + chunk cumsum (wave shfl scan, 1 barrier)
    int l0 = c*CHUNKC + tid;
    int lane = tid & 63, wv = tid >> 6;
    float negA = -expf(alog[h]);
    float lg = bf2f(zxb[((size_t)(b*SEQ+l0))*PDIM + (DI+CDIM) + h]) + dtb[h];
    float dt = softplusf_(lg);
    dts[tid] = dt;
    float s = dt*negA;
    #pragma unroll
    for (int off=1; off<64; off<<=1){
      float t = __shfl_up(s, off, 64);
      if (lane >= off) s += t;
    }
    if (lane == 63) wsum[wv] = s;
    __syncthreads();
    float pre = 0.f, tot = 0.f;
    #pragma unroll
    for (int w=0; w<4; w++){
      float wv2 = wsum[w];
      if (w < wv) pre += wv2;
      tot += wv2;
    }
    s += pre;
    acs[(size_t)bh*SEQ + l0] = s;
    dec[tid] = expf(tot - s);
    // phase 2: 4 subtiles of 64 rows: inline conv -> Xs + xbcb, then XdT/Xdec
    int srow = tid>>2, sseg = tid&3;
    int p = tid>>2, lq = tid&3;
    for (int lt2=0; lt2<4; lt2++){
      int lt = c*4 + lt2;
      __syncthreads();
      {
        int l = lt*64 + srow;
        #pragma unroll
        for (int s2=0;s2<2;s2++){
          int cg = (sseg+s2*4)*8;
          float a8[8];
          #pragma unroll
          for (int j=0;j<8;j++) a8[j] = bsh[cg+j];
          #pragma unroll
          for (int k=0;k<4;k++){
            int li = l-3+k;
            if (li>=0){
              bf16x8 v = *(const bf16x8*)(zxb + ((size_t)(b*SEQ+li))*PDIM + DI + cb0 + cg);
              #pragma unroll
              for (int j=0;j<8;j++) a8[j] += wsh[(cg+j)*4+k]*bf2f((unsigned short)v[j]);
            }
          }
          unsigned short ov[8];
          #pragma unroll
          for (int j=0;j<8;j++) ov[j] = f2bf(siluf_(a8[j]));
          *(bf16x8*)&Xs[srow*72 + cg] = *(bf16x8*)&ov[0];
          *(bf16x8*)(xbcb + ((size_t)(b*SEQ+l))*CDIM + cb0 + cg) = *(bf16x8*)&ov[0];
        }
      }
      __syncthreads();
      unsigned short o1[16], o2[16];
      #pragma unroll
      for (int li=0; li<16; li++){
        int j = lq*16+li;            // row within subtile
        int lc = lt2*64 + j;         // index within chunk
        float vv = bf2f(Xs[j*72 + p]) * dts[lc];
        o1[li] = f2bf(vv);
        o2[li] = f2bf(vv*dec[lc]);
      }
      size_t rowo = ((size_t)bh*HD + p)*SEQ + lt*64 + lq*16;
      *(bf16x8*)(XdT + rowo)     = *(bf16x8*)&o1[0];
      *(bf16x8*)(XdT + rowo + 8) = *(bf16x8*)&o1[8];
      *(bf16x8*)(Xdec + rowo)     = *(bf16x8*)&o2[0];
      *(bf16x8*)(Xdec + rowo + 8) = *(bf16x8*)&o2[8];
    }
  } else {
    // B/C sections: r -> nh2 (0,1 = B halves; 2,3 = C halves), lt, b
    int r = blk - 192;
    int nh2 = r & 3, lt = (r>>2) & 15, b = r >> 6;
    int cb0 = DI + nh2*64;               // xbcb col base
    wsh[tid] = cw[(cb0 + (tid>>2))*4 + (tid&3)];
    if (tid < 64) bsh[tid] = cb[cb0 + tid];
    __syncthreads();
    int srow = tid>>2, sseg = tid&3;
    int l = lt*64 + srow;
    #pragma unroll
    for (int s2=0;s2<2;s2++){
      int cg = (sseg+s2*4)*8;
      float a8[8];
      #pragma unroll
      for (int j=0;j<8;j++) a8[j] = bsh[cg+j];
      #pragma unroll
      for (int k=0;k<4;k++){
        int li = l-3+k;
        if (li>=0){
          bf16x8 v = *(const bf16x8*)(zxb + ((size_t)(b*SEQ+li))*PDIM + DI + cb0 + cg);
          #pragma unroll
          for (int j=0;j<8;j++) a8[j] += wsh[(cg+j)*4+k]*bf2f((unsigned short)v[j]);
        }
      }
      unsigned short ov[8];
      #pragma unroll
      for (int j=0;j<8;j++) ov[j] = f2bf(siluf_(a8[j]));
      *(bf16x8*)(xbcb + ((size_t)(b*SEQ+l))*CDIM + cb0 + cg) = *(bf16x8*)&ov[0];
      if (nh2 < 2) *(bf16x8*)&Xs[srow*72 + cg] = *(bf16x8*)&ov[0];
    }
    if (nh2 < 2){
      __syncthreads();
      int n = tid>>2, lq = tid&3;
      unsigned short o[16];
      #pragma unroll
      for (int li=0; li<16; li++) o[li] = Xs[(lq*16+li)*72 + n];
      size_t rowo = ((size_t)b*DSTATE + nh2*64 + n)*SEQ + lt*64 + lq*16;
      *(bf16x8*)(BTg + rowo)     = *(bf16x8*)&o[0];
      *(bf16x8*)(BTg + rowo + 8) = *(bf16x8*)&o[8];
    }
  }
}

// ---------------- SSD chunk states: D[p=64][n=64] = Xdec[p][:] . BT[n][:]^T ----
__global__ __launch_bounds__(256) void ssd_states2(const unsigned short* __restrict__ Xdec,
    const unsigned short* __restrict__ BTg, float* __restrict__ states){
  int blk = blockIdx.x;
  int nh = blk & 1;
  int r = blk >> 1;
  int h = r % NH;  r /= NH;
  int c = r % NCH;
  int b = r / NCH;
  int tid = threadIdx.x, wave = tid>>6, lane = tid&63, ln = lane&15, quad = lane>>4;
  __shared__ alignas(16) unsigned short As[64*264];
  __shared__ alignas(16) unsigned short Bs[64*264];
  int bh = b*NH + h;
  {
    int srow = tid>>2, sseg = tid&3;
    const unsigned short* ga = Xdec + ((size_t)bh*HD + srow)*SEQ + c*CHUNKC;
    const unsigned short* gb = BTg + ((size_t)b*DSTATE + nh*64 + srow)*SEQ + c*CHUNKC;
    #pragma unroll
    for (int s=0;s<8;s++){
      *(bf16x8*)&As[srow*264 + (sseg+s*4)*8] = *(const bf16x8*)(ga + (sseg+s*4)*8);
      *(bf16x8*)&Bs[srow*264 + (sseg+s*4)*8] = *(const bf16x8*)(gb + (sseg+s*4)*8);
    }
  }
  __syncthreads();
  f32x4 acc[4];
  #pragma unroll
  for (int nt=0;nt<4;nt++) acc[nt] = (f32x4){0.f,0.f,0.f,0.f};
  bf16x8 a[8];
  #pragma unroll
  for (int kq=0;kq<8;kq++)
    a[kq] = *(const bf16x8*)&As[(wave*16+ln)*264 + kq*32 + quad*8];
  #pragma unroll
  for (int nt=0;nt<4;nt++){
    #pragma unroll
    for (int kq=0;kq<8;kq++){
      bf16x8 bb = *(const bf16x8*)&Bs[(nt*16+ln)*264 + kq*32 + quad*8];
      acc[nt] = __builtin_amdgcn_mfma_f32_16x16x32_bf16(a[kq], bb, acc[nt], 0,0,0);
    }
  }
  float* sp = states + (((size_t)(b*NCH+c)*NH + h) << 13) + nh*64;
  #pragma unroll
  for (int nt=0;nt<4;nt++){
    #pragma unroll
    for (int r2=0;r2<4;r2++)
      sp[(size_t)(wave*16 + quad*4 + r2)*DSTATE + nt*16 + ln] = acc[nt][r2];
  }
}

// ---------------- inter-chunk scan (prev stored bf16) ----------------
__global__ __launch_bounds__(256) void ssd_scan(const float* __restrict__ states,
    const float* __restrict__ acs, unsigned short* __restrict__ prev){
  int idx = blockIdx.x*256+threadIdx.x;
  if (idx >= BATCH*NH*HD*DSTATE) return;
  int pn = idx & 8191;
  int bh = idx >> 13;
  int h = bh % NH, b = bh / NH;
  float carry = 0.f;
  #pragma unroll
  for (int c=0;c<NCH;c++){
    size_t o = (((size_t)(b*NCH+c)*NH + h) << 13) + pn;
    prev[o] = f2bf(carry);
    float dec = expf(acs[(b*NH+h)*SEQ + c*CHUNKC + CHUNKC-1]);
    carry = carry*dec + states[o];
  }
}

// ---------------- SSD diag + off-diag + skip + gate/silu + ss reduce -----------
constexpr int CW_S  = 136;
constexpr int SB_S  = 72;
constexpr int XT_S  = 72;

__global__ __launch_bounds__(256,2) void ssd_diag2(
    const unsigned short* __restrict__ xbcb, const unsigned short* __restrict__ XdT,
    const float* __restrict__ acs, const unsigned short* __restrict__ prev,
    const float* __restrict__ dskip, const unsigned short* __restrict__ zxb,
    float* __restrict__ ssum, unsigned short* __restrict__ Y){
  int blk = blockIdx.x;
  int t = blk & 3;
  int r0 = blk >> 2;
  int h = r0 % NH;  r0 /= NH;
  int c = r0 % NCH;
  int b = r0 / NCH;

  int tid = threadIdx.x;
  int wave = tid>>6, lane = tid&63, ln = lane&15, quad = lane>>4;

  __shared__ float ac[CHUNKC];
  __shared__ alignas(16) unsigned short Cw[64*CW_S];
  __shared__ alignas(16) unsigned short Pv[64*CW_S];
  __shared__ alignas(16) unsigned short Bt[64*CW_S];
  __shared__ alignas(16) unsigned short Xt[64*XT_S];
  __shared__ alignas(16) unsigned short Sb[4][16*SB_S];

  const int bh = b*NH + h;
  const size_t rowbase = (size_t)(b*SEQ + c*CHUNKC);

  ac[tid] = acs[(size_t)bh*SEQ + c*CHUNKC + tid];

  {
    int srow = tid>>2, sseg = tid&3;
    const unsigned short* gc = xbcb + (rowbase + t*64 + srow)*CDIM + DI + DSTATE;
    const unsigned short* gp = prev + (((size_t)(b*NCH+c)*NH + h) << 13) + (size_t)srow*DSTATE;
    #pragma unroll
    for (int s=0;s<4;s++){
      *(bf16x8*)&Cw[srow*CW_S + (sseg+s*4)*8] = *(const bf16x8*)(gc + (sseg+s*4)*8);
      *(bf16x8*)&Pv[srow*CW_S + (sseg+s*4)*8] = *(const bf16x8*)(gp + (sseg+s*4)*8);
    }
  }
  __syncthreads();

  bf16x8 aC[4];
  #pragma unroll
  for (int kq=0;kq<4;kq++)
    aC[kq] = *(const bf16x8*)&Cw[(wave*16+ln)*CW_S + kq*32 + quad*8];

  f32x4 yacc[4];
  #pragma unroll
  for (int ps=0;ps<4;ps++) yacc[ps] = (f32x4){0.f,0.f,0.f,0.f};

  for (int jt=0; jt<=t; jt++){
    __syncthreads();
    {
      int srow = tid>>2, sseg = tid&3;
      const unsigned short* gbm = xbcb + (rowbase + jt*64 + srow)*CDIM + DI;
      #pragma unroll
      for (int s=0;s<4;s++)
        *(bf16x8*)&Bt[srow*CW_S + (sseg+s*4)*8] = *(const bf16x8*)(gbm + (sseg+s*4)*8);
      const unsigned short* gx = XdT + ((size_t)bh*HD + srow)*SEQ + c*CHUNKC + jt*64;
      #pragma unroll
      for (int s=0;s<2;s++)
        *(bf16x8*)&Xt[srow*XT_S + (sseg+s*4)*8] = *(const bf16x8*)(gx + (sseg+s*4)*8);
    }
    __syncthreads();

    #pragma unroll
    for (int js=0; js<4; js++){
      f32x4 s = (f32x4){0.f,0.f,0.f,0.f};
      #pragma unroll
      for (int kq=0;kq<4;kq++){
        bf16x8 bB = *(const bf16x8*)&Bt[(js*16+ln)*CW_S + kq*32 + quad*8];
        s = __builtin_amdgcn_mfma_f32_16x16x32_bf16(aC[kq], bB, s, 0,0,0);
      }
      int jc = jt*64 + js*16 + ln;
      #pragma unroll
      for (int r=0;r<4;r++){
        int icl = t*64 + wave*16 + quad*4 + r;
        float d = (jc<=icl) ? (ac[icl]-ac[jc]) : -1e30f;
        Sb[wave][(quad*4+r)*SB_S + js*16 + ln] = f2bf(expf(d)*s[r]);
      }
    }
    bf16x8 aS[2];
    #pragma unroll
    for (int kq=0;kq<2;kq++)
      aS[kq] = *(const bf16x8*)&Sb[wave][ln*SB_S + kq*32 + quad*8];
    #pragma unroll
    for (int ps=0;ps<4;ps++){
      #pragma unroll
      for (int kq=0;kq<2;kq++){
        bf16x8 bX = *(const bf16x8*)&Xt[(ps*16+ln)*XT_S + kq*32 + quad*8];
        yacc[ps] = __builtin_amdgcn_mfma_f32_16x16x32_bf16(aS[kq], bX, yacc[ps], 0,0,0);
      }
    }
  }

  f32x4 oacc[4];
  #pragma unroll
  for (int ps=0;ps<4;ps++) oacc[ps] = (f32x4){0.f,0.f,0.f,0.f};
  #pragma unroll
  for (int ps=0;ps<4;ps++){
    #pragma unroll
    for (int kq=0;kq<4;kq++){
      bf16x8 bP = *(const bf16x8*)&Pv[(ps*16+ln)*CW_S + kq*32 + quad*8];
      oacc[ps] = __builtin_amdgcn_mfma_f32_16x16x32_bf16(aC[kq], bP, oacc[ps], 0,0,0);
    }
  }

  float dsk = dskip[h];
  #pragma unroll
  for (int r=0;r<4;r++){
    int icl = t*64 + wave*16 + quad*4 + r;
    float ei = expf(ac[icl]);
    size_t l = rowbase + icl;
    float rss = 0.f;
    #pragma unroll
    for (int ps=0;ps<4;ps++){
      int p = ps*16 + ln;
      float xraw = bf2f(xbcb[l*CDIM + h*HD + p]);
      float zv = bf2f(zxb[l*PDIM + h*HD + p]);
      float yg = (yacc[ps][r] + ei*oacc[ps][r] + dsk*xraw) * siluf_(zv);
      Y[l*DI + h*HD + p] = f2bf(yg);
      rss += yg*yg;
    }
    // reduce over the 16 lanes of this quad (aligned 16-lane group)
    rss += __shfl_down(rss, 8, 64);
    rss += __shfl_down(rss, 4, 64);
    rss += __shfl_down(rss, 2, 64);
    rss += __shfl_down(rss, 1, 64);
    if (ln == 0) atomicAdd(&ssum[l], rss);
  }
}

// ---------------- final pooling + head -----------------------------------------
__global__ __launch_bounds__(256) void mean_pool(const float* __restrict__ hn,
    float* __restrict__ pooled){
  int idx = blockIdx.x*256+threadIdx.x;
  if (idx >= BATCH*DM) return;
  int b = idx / DM, d = idx % DM;
  float s = 0.f;
  for (int l=0;l<SEQ;l++) s += hn[((size_t)(b*SEQ+l))*DM + d];
  pooled[idx] = s * (1.f/SEQ);
}

__global__ __launch_bounds__(512) void head_k(const float* __restrict__ pooled,
    const float* __restrict__ w1, const float* __restrict__ b1,
    const float* __restrict__ g, const float* __restrict__ bb,
    const float* __restrict__ mn, const float* __restrict__ vr,
    const float* __restrict__ w2, const float* __restrict__ b2,
    float* __restrict__ out){
  int b = blockIdx.x;
  int j = threadIdx.x;
  __shared__ float f[512];
  __shared__ float pl[DM];
  for (int t=j; t<DM; t+=512) pl[t] = pooled[b*DM+t];
  __syncthreads();
  float s = b1[j];
  for (int k=0;k<DM;k++) s += pl[k]*w1[k*512+j];
  s = (s-mn[j])*(g[j]*rsqrtf(vr[j]+EPSF)) + bb[j];
  f[j] = fmaxf(s,0.f);
  __syncthreads();
  if (j < 27){
    float o = b2[j];
    for (int k=0;k<512;k++) o += f[k]*w2[k*27+j];
    out[b*27+j] = o;
  }
}

extern "C" void kernel_launch(void* const* d_in, const int* in_sizes, int n_in,
                              void* d_out, int out_size, void* d_ws, size_t ws_size,
                              hipStream_t stream){
  const float* x      = (const float*)d_in[0];
  const float* c1_w   = (const float*)d_in[1];
  const float* c1_b   = (const float*)d_in[2];
  const float* bn1_g  = (const float*)d_in[3];
  const float* bn1_b  = (const float*)d_in[4];
  const float* bn1_m  = (const float*)d_in[5];
  const float* bn1_v  = (const float*)d_in[6];
  const float* c2_w   = (const float*)d_in[7];
  const float* c2_b   = (const float*)d_in[8];
  const float* bn2_g  = (const float*)d_in[9];
  const float* bn2_b  = (const float*)d_in[10];
  const float* bn2_m  = (const float*)d_in[11];
  const float* bn2_v  = (const float*)d_in[12];
  const float* c3_w   = (const float*)d_in[13];
  const float* c3_b   = (const float*)d_in[14];
  const float* bn3_g  = (const float*)d_in[15];
  const float* bn3_b  = (const float*)d_in[16];
  const float* bn3_m  = (const float*)d_in[17];
  const float* bn3_v  = (const float*)d_in[18];
  const float* ln_w   = (const float*)d_in[19];
  const float* inpw   = (const float*)d_in[20];
  const float* convw  = (const float*)d_in[21];
  const float* convb  = (const float*)d_in[22];
  const float* dtb    = (const float*)d_in[23];
  const float* alog   = (const float*)d_in[24];
  const float* dskip  = (const float*)d_in[25];
  const float* gnw    = (const float*)d_in[26];
  const float* outw   = (const float*)d_in[27];
  const float* normfw = (const float*)d_in[28];
  const float* fc1w   = (const float*)d_in[29];
  const float* fc1b   = (const float*)d_in[30];
  const float* bncg   = (const float*)d_in[31];
  const float* bncb   = (const float*)d_in[32];
  const float* bncm   = (const float*)d_in[33];
  const float* bncv   = (const float*)d_in[34];
  const float* fc2w   = (const float*)d_in[35];
  const float* fc2b   = (const float*)d_in[36];
  (void)in_sizes; (void)n_in; (void)out_size;

  char* ws = (char*)d_ws;
  size_t off = 0;
  auto alloc = [&](size_t bytes){
    char* p = ws + off;
    off += (bytes + 255) & ~(size_t)255;
    return (void*)p;
  };
  float* h1  = (float*)alloc((size_t)BATCH*192*LS1*4);
  float* h   = (float*)alloc((size_t)BATCH*SEQ*DM*4);
  float* hn  = (float*)alloc((size_t)BATCH*SEQ*DM*4);
  unsigned short* zxb = (unsigned short*)alloc((size_t)BATCH*SEQ*PDIM*2);
  unsigned short* xbcb= (unsigned short*)alloc((size_t)BATCH*SEQ*CDIM*2);
  float* acs = (float*)alloc((size_t)BATCH*NH*SEQ*4);
  float* st  = (float*)alloc((size_t)BATCH*NCH*NH*HD*DSTATE*4);
  unsigned short* pv  = (unsigned short*)alloc((size_t)BATCH*NCH*NH*HD*DSTATE*2);
  unsigned short* Y   = (unsigned short*)alloc((size_t)BATCH*SEQ*DI*2);
  float* pooled = (float*)alloc((size_t)BATCH*DM*4);
  unsigned short* hnb   = (unsigned short*)alloc((size_t)BATCH*SEQ*DM*2);
  float* ssum = (float*)alloc((size_t)BATCH*SEQ*4);
  unsigned short* XdTg  = (unsigned short*)alloc((size_t)BATCH*NH*HD*SEQ*2);
  unsigned short* Xdecg = (unsigned short*)alloc((size_t)BATCH*NH*HD*SEQ*2);
  unsigned short* BTg   = (unsigned short*)alloc((size_t)BATCH*DSTATE*SEQ*2);
  unsigned short* xT2   = (unsigned short*)alloc((size_t)BATCH*XT2_BSTRIDE*2);
  unsigned short* xT3   = (unsigned short*)alloc((size_t)BATCH*XT3_BSTRIDE*2);
  unsigned short* wt2   = (unsigned short*)alloc((size_t)384*576*2);
  unsigned short* wt3   = (unsigned short*)alloc((size_t)768*1152*2);

  // weight buffers: all-layer (hoisted) if ws allows, else per-layer fallback
  const size_t wtin_l  = (size_t)PPAD*DM;     // elems per layer
  const size_t wtout_l = (size_t)DM*DI;
  size_t base_off = off;
  size_t big_bytes = (wtin_l + wtout_l)*NLAYER*2 + 512;
  bool big = (ws_size >= base_off + big_bytes);
  unsigned short *wtinA, *wtoutA;
  if (big){
    wtinA  = (unsigned short*)alloc(wtin_l*NLAYER*2);
    wtoutA = (unsigned short*)alloc(wtout_l*NLAYER*2);
  } else {
    wtinA  = (unsigned short*)alloc(wtin_l*2);
    wtoutA = (unsigned short*)alloc(wtout_l*2);
  }

  // ---- one-time weight prep ----
  wt_reorder<<<(384*192*3+255)/256,256,0,stream>>>(c2_w, wt2, 384, 192, 3);
  wt_reorder<<<(768*384*3+255)/256,256,0,stream>>>(c3_w, wt3, 768, 384, 3);
  zero_rows3<<<(2*2*384+255)/256,256,0,stream>>>(xT3);
  if (big){
    transpose_cvt_l<<<dim3(PPAD/32, DM/32, NLAYER),256,0,stream>>>(
        inpw, wtinA, DM, PDIM, PPAD, (size_t)DM*PDIM, wtin_l, nullptr, 0);
    // fold gnw into out_proj weight (rms column weight is the GEMM K dim)
    transpose_cvt_l<<<dim3(DM/32, DI/32, NLAYER),256,0,stream>>>(
        outw, wtoutA, DI, DM, DM, (size_t)DI*DM, wtout_l, gnw, (size_t)DI);
  }

  // ---- stem ----
  conv_stem1<<<(BATCH*192*LS1+255)/256,256,0,stream>>>(x, c1_w,c1_b, bn1_g,bn1_b,bn1_m,bn1_v, h1);
  transpose_pad_bf<<<dim3(LS1/32, 192/32, BATCH),256,0,stream>>>(
      h1, xT2, 192, LS1, (size_t)192*LS1, XT2_BSTRIDE);
  gemm_stem<0><<<dim3(384/128, 16),256,0,stream>>>(
      xT2, wt2, c2_b, bn2_g, bn2_b, bn2_m, bn2_v, xT3, nullptr,
      576, 384, XT2_BSTRIDE);
  gemm_stem<1><<<dim3(768/128, 16),256,0,stream>>>(
      xT3, wt3, c3_b, bn3_g, bn3_b, bn3_m, bn3_v, nullptr, h,
      1152, 384, XT3_BSTRIDE);

  const int M = BATCH*SEQ;  // 2048
  for (int l=0; l<NLAYER; l++){
    unsigned short* wtin  = big ? (wtinA  + (size_t)l*wtin_l)  : wtinA;
    unsigned short* wtout = big ? (wtoutA + (size_t)l*wtout_l) : wtoutA;
    if (!big){
      transpose_cvt_l<<<dim3(PPAD/32, DM/32, 1),256,0,stream>>>(
          inpw + (size_t)l*DM*PDIM, wtin, DM, PDIM, PPAD, 0, 0, nullptr, 0);
      transpose_cvt_l<<<dim3(DM/32, DI/32, 1),256,0,stream>>>(
          outw + (size_t)l*DI*DM, wtout, DI, DM, DM, 0, 0, gnw + (size_t)l*DI, 0);
    }

    rmsnorm768<1><<<M,256,0,stream>>>(h, ln_w + (size_t)l*DM, nullptr, hnb);
    gemm_bf16<2><<<dim3(PPAD/128, M/128),256,0,stream>>>(hnb, wtin, nullptr, zxb, PDIM, DM, PDIM);
    prep_fused<<<320,256,0,stream>>>(zxb, xbcb, convw + (size_t)l*CDIM*4, convb + (size_t)l*CDIM,
        dtb + l*NH, alog + l*NH, acs, XdTg, Xdecg, BTg, ssum);
    ssd_states2<<<BATCH*NCH*NH*2,256,0,stream>>>(Xdecg, BTg, st);
    ssd_scan<<<(BATCH*NH*HD*DSTATE+255)/256,256,0,stream>>>(st, acs, pv);
    ssd_diag2<<<BATCH*NCH*NH*4,256,0,stream>>>(xbcb, XdTg, acs, pv, dskip + l*NH, zxb, ssum, Y);
    gemm_out<<<dim3(DM/64, M/64),256,0,stream>>>(Y, wtout, ssum, h, DM, DI);
  }

  rmsnorm768<0><<<M,256,0,stream>>>(h, normfw, hn, nullptr);
  mean_pool<<<(BATCH*DM+255)/256,256,0,stream>>>(hn, pooled);
  head_k<<<BATCH,512,0,stream>>>(pooled, fc1w, fc1b, bncg,bncb,bncm,bncv, fc2w, fc2b, (float*)d_out);
}